// Round 1
// baseline (1580.812 us; speedup 1.0000x reference)
//
#include <hip/hip_runtime.h>
#include <hip/hip_bf16.h>
#include <math.h>

#define NN 50000
#define NE 800000
#define DIN1 64
#define NHEAD 4
#define CH 32
#define HC 128
#define EDIM 16
#define NG 2000

__device__ __forceinline__ float lrelu(float x, float s) { return x > 0.f ? x : s * x; }

// ---------------- we_a precompute: we_a[l][d][h] = sum_c We_l[d, h*32+c]*ae_l[h,c]
__global__ __launch_bounds__(256) void k_we_a(
    const float* __restrict__ We1, const float* __restrict__ ae1,
    const float* __restrict__ We2, const float* __restrict__ ae2,
    const float* __restrict__ We3, const float* __restrict__ ae3,
    float* __restrict__ we_a) {
  int t = threadIdx.x;
  if (t >= 3 * EDIM * NHEAD) return;
  int l = t / (EDIM * NHEAD);
  int rem = t % (EDIM * NHEAD);
  int d = rem / NHEAD, h = rem % NHEAD;
  const float* We = (l == 0) ? We1 : ((l == 1) ? We2 : We3);
  const float* ae = (l == 0) ? ae1 : ((l == 1) ? ae2 : ae3);
  float s = 0.f;
  for (int c = 0; c < CH; ++c) s += We[d * HC + h * CH + c] * ae[h * CH + c];
  we_a[t] = s;
}

// ---------------- CSR build
__global__ __launch_bounds__(256) void k_hist(const int* __restrict__ dst, int* __restrict__ cnt) {
  int e = blockIdx.x * 256 + threadIdx.x;
  if (e < NE) atomicAdd(&cnt[dst[e]], 1);
}

__global__ __launch_bounds__(256) void k_scan1(const int* __restrict__ cnt, int* __restrict__ row_start,
                                               int* __restrict__ aux) {
  __shared__ int s[256];
  int t = threadIdx.x;
  int i = blockIdx.x * 256 + t;
  int v = (i < NN) ? cnt[i] : 0;
  s[t] = v;
  __syncthreads();
  for (int off = 1; off < 256; off <<= 1) {
    int tv = (t >= off) ? s[t - off] : 0;
    __syncthreads();
    s[t] += tv;
    __syncthreads();
  }
  if (i < NN) row_start[i] = s[t] - v;  // exclusive within block
  if (t == 255) aux[blockIdx.x] = s[255];
}

__global__ __launch_bounds__(256) void k_scan2(int* __restrict__ aux, int nb) {
  __shared__ int s[256];
  int t = threadIdx.x;
  int v = (t < nb) ? aux[t] : 0;
  s[t] = v;
  __syncthreads();
  for (int off = 1; off < 256; off <<= 1) {
    int tv = (t >= off) ? s[t - off] : 0;
    __syncthreads();
    s[t] += tv;
    __syncthreads();
  }
  if (t < nb) aux[t] = s[t] - v;  // exclusive block offsets
}

__global__ __launch_bounds__(256) void k_scan3(int* __restrict__ row_start, const int* __restrict__ aux) {
  int i = blockIdx.x * 256 + threadIdx.x;
  if (i < NN) row_start[i] += aux[i >> 8];
  else if (i == NN) row_start[NN] = NE;
}

__global__ __launch_bounds__(256) void k_scatter(const int* __restrict__ dst, const int* __restrict__ row_start,
                                                 int* __restrict__ fill, int* __restrict__ perm) {
  int e = blockIdx.x * 256 + threadIdx.x;
  if (e >= NE) return;
  int d = dst[e];
  int p = atomicAdd(&fill[d], 1);
  perm[row_start[d] + p] = e;
}

// ---------------- graph ranges (batch is sorted)
__global__ __launch_bounds__(256) void k_gstart(const int* __restrict__ batch, int* __restrict__ gs) {
  int i = blockIdx.x * 256 + threadIdx.x;
  if (i >= NN) return;
  int b = batch[i];
  if (i == 0) {
    for (int g = 0; g <= b; ++g) gs[g] = 0;
  } else {
    int pb = batch[i - 1];
    for (int g = pb + 1; g <= b; ++g) gs[g] = i;
  }
  if (i == NN - 1) {
    for (int g = b + 1; g <= NG; ++g) gs[g] = NN;
  }
}

// ---------------- conv GEMM: out[n,0:128] = X[n,0:DIN] @ W[DIN,128]
// 128 rows x 128 cols per block, 256 threads, 8x8 register tile.
template <int DIN>
__global__ __launch_bounds__(256) void k_gemm_conv(const float* __restrict__ X, const float* __restrict__ W,
                                                   float* __restrict__ out) {
  __shared__ float Xs[32][132];  // [k][row], pad keeps float4 alignment
  __shared__ float Ws[32][128];  // [k][col]
  int t = threadIdx.x;
  int n0 = blockIdx.x * 128;
  int tj = t & 15, tn = t >> 4;
  float acc[8][8];
#pragma unroll
  for (int a = 0; a < 8; ++a)
#pragma unroll
    for (int b = 0; b < 8; ++b) acc[a][b] = 0.f;

  for (int k0 = 0; k0 < DIN; k0 += 32) {
    __syncthreads();
#pragma unroll
    for (int i = 0; i < 16; ++i) {
      int q = t + 256 * i;
      int r = q & 31, row = q >> 5;
      int gn = n0 + row;
      Xs[r][row] = (gn < NN) ? X[(size_t)gn * DIN + k0 + r] : 0.f;
    }
#pragma unroll
    for (int i = 0; i < 16; ++i) {
      int q = t + 256 * i;
      int r = q >> 7, j = q & 127;
      Ws[r][j] = W[(k0 + r) * HC + j];
    }
    __syncthreads();
#pragma unroll
    for (int r = 0; r < 32; ++r) {
      float4 xa = *(const float4*)&Xs[r][tn * 8];
      float4 xb = *(const float4*)&Xs[r][tn * 8 + 4];
      float4 wa = *(const float4*)&Ws[r][tj * 8];
      float4 wb = *(const float4*)&Ws[r][tj * 8 + 4];
      float xr[8] = {xa.x, xa.y, xa.z, xa.w, xb.x, xb.y, xb.z, xb.w};
      float wr[8] = {wa.x, wa.y, wa.z, wa.w, wb.x, wb.y, wb.z, wb.w};
#pragma unroll
      for (int a = 0; a < 8; ++a)
#pragma unroll
        for (int b = 0; b < 8; ++b) acc[a][b] += xr[a] * wr[b];
    }
  }
#pragma unroll
  for (int a = 0; a < 8; ++a) {
    int n = n0 + tn * 8 + a;
    if (n < NN) {
      float4 v0 = make_float4(acc[a][0], acc[a][1], acc[a][2], acc[a][3]);
      float4 v1 = make_float4(acc[a][4], acc[a][5], acc[a][6], acc[a][7]);
      *(float4*)&out[(size_t)n * HC + tj * 8] = v0;
      *(float4*)&out[(size_t)n * HC + tj * 8 + 4] = v1;
    }
  }
}

// ---------------- per-node attention dots: asrc[n,h], adst[n,h]
__global__ __launch_bounds__(256) void k_attn_node(const float* __restrict__ ht, const float* __restrict__ a_s,
                                                   const float* __restrict__ a_d, float* __restrict__ asrc,
                                                   float* __restrict__ adst) {
  __shared__ float ss[HC], sd[HC];
  int t = threadIdx.x;
  if (t < HC) {
    ss[t] = a_s[t];
    sd[t] = a_d[t];
  }
  __syncthreads();
  int p = blockIdx.x * 256 + t;
  if (p >= NN * NHEAD) return;
  int n = p >> 2, h = p & 3;
  const float* hrow = &ht[(size_t)n * HC + h * CH];
  float sa = 0.f, da = 0.f;
#pragma unroll
  for (int k = 0; k < CH; k += 4) {
    float4 hv = *(const float4*)&hrow[k];
    float4 av = *(const float4*)&ss[h * CH + k];
    float4 dv = *(const float4*)&sd[h * CH + k];
    sa += hv.x * av.x + hv.y * av.y + hv.z * av.z + hv.w * av.w;
    da += hv.x * dv.x + hv.y * dv.y + hv.z * dv.z + hv.w * dv.w;
  }
  asrc[p] = sa;
  adst[p] = da;
}

// ---------------- per-edge: ex[e,h] = exp(leaky(asrc[src]+adst[dst]+edge_attr@we_a, 0.2))
__global__ __launch_bounds__(256) void k_alpha(const int* __restrict__ src, const int* __restrict__ dst,
                                               const float* __restrict__ edge_attr, const float* __restrict__ wea,
                                               const float* __restrict__ asrc, const float* __restrict__ adst,
                                               float* __restrict__ exbuf) {
  __shared__ float wl[EDIM * NHEAD];
  int t = threadIdx.x;
  if (t < EDIM * NHEAD) wl[t] = wea[t];
  __syncthreads();
  int e = blockIdx.x * 256 + t;
  if (e >= NE) return;
  int s = src[e], d = dst[e];
  float4 as4 = *(const float4*)&asrc[s * 4];
  float4 ad4 = *(const float4*)&adst[d * 4];
  float ae[4] = {0.f, 0.f, 0.f, 0.f};
#pragma unroll
  for (int k = 0; k < EDIM; ++k) {
    float ev = edge_attr[(size_t)e * EDIM + k];
    ae[0] += ev * wl[k * 4 + 0];
    ae[1] += ev * wl[k * 4 + 1];
    ae[2] += ev * wl[k * 4 + 2];
    ae[3] += ev * wl[k * 4 + 3];
  }
  float4 o;
  o.x = __expf(lrelu(as4.x + ad4.x + ae[0], 0.2f));
  o.y = __expf(lrelu(as4.y + ad4.y + ae[1], 0.2f));
  o.z = __expf(lrelu(as4.z + ad4.z + ae[2], 0.2f));
  o.w = __expf(lrelu(as4.w + ad4.w + ae[3], 0.2f));
  *(float4*)&exbuf[e * 4] = o;
}

// ---------------- aggregation: one wave per node. hout[n,c] = inv[h(c)]*sum_e ex[e,h]*ht[src,c] + b[c]
__global__ __launch_bounds__(256) void k_aggregate(const float* __restrict__ ht, const float* __restrict__ exbuf,
                                                   const int* __restrict__ row_start, const int* __restrict__ perm,
                                                   const int* __restrict__ src, const float* __restrict__ bias,
                                                   float* __restrict__ hout) {
  int t = threadIdx.x;
  int lane = t & 63;
  int n = blockIdx.x * 4 + (t >> 6);
  if (n >= NN) return;
  int rs = row_start[n], re = row_start[n + 1];
  float d0 = 0.f, d1 = 0.f, d2 = 0.f, d3 = 0.f;
  for (int i = rs + lane; i < re; i += 64) {
    int e = perm[i];
    float4 ex = *(const float4*)&exbuf[e * 4];
    d0 += ex.x; d1 += ex.y; d2 += ex.z; d3 += ex.w;
  }
#pragma unroll
  for (int m = 1; m < 64; m <<= 1) {
    d0 += __shfl_xor(d0, m, 64);
    d1 += __shfl_xor(d1, m, 64);
    d2 += __shfl_xor(d2, m, 64);
    d3 += __shfl_xor(d3, m, 64);
  }
  float inv0 = 1.f / (d0 + 1e-16f), inv1 = 1.f / (d1 + 1e-16f);
  float inv2 = 1.f / (d2 + 1e-16f), inv3 = 1.f / (d3 + 1e-16f);
  int c0 = lane, c1 = lane + 64;
  int h0 = lane >> 5, h1 = 2 + (lane >> 5);
  float acc0 = 0.f, acc1 = 0.f;
  for (int i = rs; i < re; ++i) {
    int e = perm[i];
    int s = src[e];
    float e0 = exbuf[e * 4 + h0];
    float e1 = exbuf[e * 4 + h1];
    acc0 += e0 * ht[(size_t)s * HC + c0];
    acc1 += e1 * ht[(size_t)s * HC + c1];
  }
  float iv0 = (h0 == 0) ? inv0 : inv1;
  float iv1 = (h1 == 2) ? inv2 : inv3;
  hout[(size_t)n * HC + c0] = acc0 * iv0 + bias[c0];
  hout[(size_t)n * HC + c1] = acc1 * iv1 + bias[c1];
}

// ---------------- global add pool over sorted batch ranges
__global__ __launch_bounds__(128) void k_pool(const float* __restrict__ h3, const int* __restrict__ gs,
                                              float* __restrict__ hpool) {
  int g = blockIdx.x;
  int j = threadIdx.x;
  int s = gs[g], e = gs[g + 1];
  float acc = 0.f;
  for (int i = s; i < e; ++i) acc += h3[(size_t)i * HC + j];
  hpool[(size_t)g * HC + j] = acc;
}

// ---------------- ph[g,0:512] = hpool[g,0:128] @ lw1[384:512, 0:512]
__global__ __launch_bounds__(256) void k_pool_gemm(const float* __restrict__ hpool, const float* __restrict__ lw1,
                                                   float* __restrict__ ph) {
  __shared__ float hp[16][128];
  int t = threadIdx.x;
  int j0 = blockIdx.x * 128;
  int g0 = blockIdx.y * 16;
  int jj = t & 127, gg = t >> 7;  // gg in {0,1}
#pragma unroll
  for (int i = 0; i < 8; ++i) {
    int q = t + 256 * i;
    int row = q >> 7, col = q & 127;
    hp[row][col] = hpool[(size_t)(g0 + row) * HC + col];
  }
  __syncthreads();
  float acc[8];
#pragma unroll
  for (int i = 0; i < 8; ++i) acc[i] = 0.f;
  for (int k = 0; k < HC; ++k) {
    float wv = lw1[(size_t)(384 + k) * 512 + j0 + jj];
#pragma unroll
    for (int gi = 0; gi < 8; ++gi) acc[gi] += hp[gg + 2 * gi][k] * wv;
  }
#pragma unroll
  for (int gi = 0; gi < 8; ++gi) ph[(size_t)(g0 + gg + 2 * gi) * 512 + j0 + jj] = acc[gi];
}

__global__ __launch_bounds__(256) void k_outinit(float* __restrict__ out, const float* __restrict__ lb2) {
  int i = blockIdx.x * 256 + threadIdx.x;
  if (i < NN) out[i] = lb2[0];
}

// ---------------- fused MLP: hidden = leaky([h1|h2|h3]@lw1[0:384] + ph[batch] + lb1, .01); out += hidden@lw2
__global__ __launch_bounds__(256) void k_mlp(const float* __restrict__ h1, const float* __restrict__ h2,
                                             const float* __restrict__ h3, const float* __restrict__ ph,
                                             const int* __restrict__ batch, const float* __restrict__ lw1,
                                             const float* __restrict__ lb1, const float* __restrict__ lw2,
                                             float* __restrict__ out) {
  __shared__ float Xs[32][132];
  __shared__ float Ws[32][128];
  int t = threadIdx.x;
  int n0 = blockIdx.x * 128;
  int j0 = blockIdx.y * 128;
  int tj = t & 15, tn = t >> 4;
  float acc[8][8];
#pragma unroll
  for (int a = 0; a < 8; ++a)
#pragma unroll
    for (int b = 0; b < 8; ++b) acc[a][b] = 0.f;

  for (int kt = 0; kt < 12; ++kt) {
    const float* Xsrc = (kt < 4) ? h1 : ((kt < 8) ? h2 : h3);
    int kc = (kt & 3) * 32;
    __syncthreads();
#pragma unroll
    for (int i = 0; i < 16; ++i) {
      int q = t + 256 * i;
      int r = q & 31, row = q >> 5;
      int gn = n0 + row;
      Xs[r][row] = (gn < NN) ? Xsrc[(size_t)gn * HC + kc + r] : 0.f;
    }
#pragma unroll
    for (int i = 0; i < 16; ++i) {
      int q = t + 256 * i;
      int r = q >> 7, j = q & 127;
      Ws[r][j] = lw1[(size_t)(kt * 32 + r) * 512 + j0 + j];
    }
    __syncthreads();
#pragma unroll
    for (int r = 0; r < 32; ++r) {
      float4 xa = *(const float4*)&Xs[r][tn * 8];
      float4 xb = *(const float4*)&Xs[r][tn * 8 + 4];
      float4 wa = *(const float4*)&Ws[r][tj * 8];
      float4 wb = *(const float4*)&Ws[r][tj * 8 + 4];
      float xr[8] = {xa.x, xa.y, xa.z, xa.w, xb.x, xb.y, xb.z, xb.w};
      float wr[8] = {wa.x, wa.y, wa.z, wa.w, wb.x, wb.y, wb.z, wb.w};
#pragma unroll
      for (int a = 0; a < 8; ++a)
#pragma unroll
        for (int b = 0; b < 8; ++b) acc[a][b] += xr[a] * wr[b];
    }
  }
  // epilogue: + ph[batch[n]] + lb1, leaky(0.01), dot with lw2, reduce 16 lanes, one atomic
#pragma unroll
  for (int a = 0; a < 8; ++a) {
    int n = n0 + tn * 8 + a;
    float partial = 0.f;
    if (n < NN) {
      int bg = batch[n];
#pragma unroll
      for (int qb = 0; qb < 8; qb += 4) {
        int j = j0 + tj * 8 + qb;
        float4 pb = *(const float4*)&ph[(size_t)bg * 512 + j];
        float4 lb = *(const float4*)&lb1[j];
        float4 l2 = *(const float4*)&lw2[j];
        float v;
        v = acc[a][qb + 0] + pb.x + lb.x; partial += lrelu(v, 0.01f) * l2.x;
        v = acc[a][qb + 1] + pb.y + lb.y; partial += lrelu(v, 0.01f) * l2.y;
        v = acc[a][qb + 2] + pb.z + lb.z; partial += lrelu(v, 0.01f) * l2.z;
        v = acc[a][qb + 3] + pb.w + lb.w; partial += lrelu(v, 0.01f) * l2.w;
      }
    }
#pragma unroll
    for (int m = 1; m < 16; m <<= 1) partial += __shfl_xor(partial, m, 16);
    if (tj == 0 && n < NN) atomicAdd(&out[n], partial);
  }
}

extern "C" void kernel_launch(void* const* d_in, const int* in_sizes, int n_in,
                              void* d_out, int out_size, void* d_ws, size_t ws_size,
                              hipStream_t stream) {
  const float* x = (const float*)d_in[0];
  const int* edge_index = (const int*)d_in[1];
  const int* src = edge_index;
  const int* dstp = edge_index + NE;
  const float* edge_attr = (const float*)d_in[2];
  const int* batch = (const int*)d_in[3];
  const float* W[3] = {(const float*)d_in[4], (const float*)d_in[10], (const float*)d_in[16]};
  const float* as_[3] = {(const float*)d_in[5], (const float*)d_in[11], (const float*)d_in[17]};
  const float* ad_[3] = {(const float*)d_in[6], (const float*)d_in[12], (const float*)d_in[18]};
  const float* We_[3] = {(const float*)d_in[7], (const float*)d_in[13], (const float*)d_in[19]};
  const float* ae_[3] = {(const float*)d_in[8], (const float*)d_in[14], (const float*)d_in[20]};
  const float* b_[3] = {(const float*)d_in[9], (const float*)d_in[15], (const float*)d_in[21]};
  const float* lw1 = (const float*)d_in[22];
  const float* lb1 = (const float*)d_in[23];
  const float* lw2 = (const float*)d_in[24];
  const float* lb2 = (const float*)d_in[25];
  float* out = (float*)d_out;

  // workspace carve-up
  float* f = (float*)d_ws;
  size_t o = 0;
  float* ht = f + o;    o += (size_t)NN * HC;
  float* h1 = f + o;    o += (size_t)NN * HC;
  float* h2 = f + o;    o += (size_t)NN * HC;
  float* h3 = f + o;    o += (size_t)NN * HC;
  float* asrc = f + o;  o += (size_t)NN * NHEAD;
  float* adst = f + o;  o += (size_t)NN * NHEAD;
  float* exbuf = f + o; o += (size_t)NE * NHEAD;
  float* wea = f + o;   o += 256;
  float* hpool = f + o; o += (size_t)NG * HC;
  float* ph = f + o;    o += (size_t)NG * 512;
  int* row_start = (int*)(f + o);
  int* cnt = row_start + (NN + 1);
  int* fill = cnt + NN;
  int* aux = fill + NN;
  int* gs = aux + 256;
  int* perm = gs + (NG + 1);

  const int NB = (NN + 255) / 256;           // 196 scan blocks
  const int EB = (NE + 255) / 256;           // 3125 edge blocks

  hipMemsetAsync(cnt, 0, (size_t)2 * NN * sizeof(int), stream);  // cnt + fill

  k_we_a<<<1, 256, 0, stream>>>(We_[0], ae_[0], We_[1], ae_[1], We_[2], ae_[2], wea);
  k_hist<<<EB, 256, 0, stream>>>(dstp, cnt);
  k_scan1<<<NB, 256, 0, stream>>>(cnt, row_start, aux);
  k_scan2<<<1, 256, 0, stream>>>(aux, NB);
  k_scan3<<<NB, 256, 0, stream>>>(row_start, aux);
  k_scatter<<<EB, 256, 0, stream>>>(dstp, row_start, fill, perm);
  k_gstart<<<NB, 256, 0, stream>>>(batch, gs);
  k_outinit<<<NB, 256, 0, stream>>>(out, lb2);

  float* houts[3] = {h1, h2, h3};
  for (int l = 0; l < 3; ++l) {
    const float* xin = (l == 0) ? x : houts[l - 1];
    if (l == 0)
      k_gemm_conv<DIN1><<<(NN + 127) / 128, 256, 0, stream>>>(xin, W[l], ht);
    else
      k_gemm_conv<HC><<<(NN + 127) / 128, 256, 0, stream>>>(xin, W[l], ht);
    k_attn_node<<<(NN * NHEAD + 255) / 256, 256, 0, stream>>>(ht, as_[l], ad_[l], asrc, adst);
    k_alpha<<<EB, 256, 0, stream>>>(src, dstp, edge_attr, wea + l * 64, asrc, adst, exbuf);
    k_aggregate<<<(NN + 3) / 4, 256, 0, stream>>>(ht, exbuf, row_start, perm, src, b_[l], houts[l]);
  }

  k_pool<<<NG, 128, 0, stream>>>(h3, gs, hpool);
  k_pool_gemm<<<dim3(4, NG / 16), 256, 0, stream>>>(hpool, lw1, ph);
  k_mlp<<<dim3((NN + 127) / 128, 4), 256, 0, stream>>>(h1, h2, h3, ph, batch, lw1, lb1, lw2, out);
}

// Round 2
// 999.683 us; speedup vs baseline: 1.5813x; 1.5813x over previous
//
#include <hip/hip_runtime.h>
#include <hip/hip_bf16.h>
#include <math.h>

#define NN 50000
#define NE 800000
#define DIN1 64
#define NHEAD 4
#define CH 32
#define HC 128
#define EDIM 16
#define NG 2000
#define SP 56  // LDS k-stride in bf16 elems (112B: 16B-aligned, 8-row bank cycle -> conflict-free b128)

typedef __attribute__((ext_vector_type(8))) short short8;
typedef __attribute__((ext_vector_type(4))) float floatx4;

__device__ __forceinline__ float lrelu(float x, float s) { return x > 0.f ? x : s * x; }

__device__ __forceinline__ unsigned short f2bf(float x) {
  unsigned int u = __float_as_uint(x);
  u += 0x7fff + ((u >> 16) & 1);  // RNE
  return (unsigned short)(u >> 16);
}

// ---------------- we_a precompute: we_a[l][d][h] = sum_c We_l[d, h*32+c]*ae_l[h,c]
__global__ __launch_bounds__(256) void k_we_a(
    const float* __restrict__ We1, const float* __restrict__ ae1,
    const float* __restrict__ We2, const float* __restrict__ ae2,
    const float* __restrict__ We3, const float* __restrict__ ae3,
    float* __restrict__ we_a) {
  int t = threadIdx.x;
  if (t >= 3 * EDIM * NHEAD) return;
  int l = t / (EDIM * NHEAD);
  int rem = t % (EDIM * NHEAD);
  int d = rem / NHEAD, h = rem % NHEAD;
  const float* We = (l == 0) ? We1 : ((l == 1) ? We2 : We3);
  const float* ae = (l == 0) ? ae1 : ((l == 1) ? ae2 : ae3);
  float s = 0.f;
  for (int c = 0; c < CH; ++c) s += We[d * HC + h * CH + c] * ae[h * CH + c];
  we_a[t] = s;
}

// ---------------- lw1 rows 0:384 -> transposed bf16 [512][384]
__global__ __launch_bounds__(256) void k_lw1t(const float* __restrict__ lw1, unsigned short* __restrict__ lw1tb) {
  int i = blockIdx.x * 256 + threadIdx.x;
  if (i >= 512 * 384) return;
  int n = i / 384, k = i % 384;
  lw1tb[i] = f2bf(lw1[(size_t)k * 512 + n]);
}

// ---------------- CSR build
__global__ __launch_bounds__(256) void k_hist(const int* __restrict__ dst, int* __restrict__ cnt) {
  int e = blockIdx.x * 256 + threadIdx.x;
  if (e < NE) atomicAdd(&cnt[dst[e]], 1);
}

__global__ __launch_bounds__(256) void k_scan1(const int* __restrict__ cnt, int* __restrict__ row_start,
                                               int* __restrict__ aux) {
  __shared__ int s[256];
  int t = threadIdx.x;
  int i = blockIdx.x * 256 + t;
  int v = (i < NN) ? cnt[i] : 0;
  s[t] = v;
  __syncthreads();
  for (int off = 1; off < 256; off <<= 1) {
    int tv = (t >= off) ? s[t - off] : 0;
    __syncthreads();
    s[t] += tv;
    __syncthreads();
  }
  if (i < NN) row_start[i] = s[t] - v;
  if (t == 255) aux[blockIdx.x] = s[255];
}

__global__ __launch_bounds__(256) void k_scan2(int* __restrict__ aux, int nb) {
  __shared__ int s[256];
  int t = threadIdx.x;
  int v = (t < nb) ? aux[t] : 0;
  s[t] = v;
  __syncthreads();
  for (int off = 1; off < 256; off <<= 1) {
    int tv = (t >= off) ? s[t - off] : 0;
    __syncthreads();
    s[t] += tv;
    __syncthreads();
  }
  if (t < nb) aux[t] = s[t] - v;
}

__global__ __launch_bounds__(256) void k_scan3(int* __restrict__ row_start, const int* __restrict__ aux) {
  int i = blockIdx.x * 256 + threadIdx.x;
  if (i < NN) row_start[i] += aux[i >> 8];
  else if (i == NN) row_start[NN] = NE;
}

__global__ __launch_bounds__(256) void k_scatter(const int* __restrict__ dst, const int* __restrict__ row_start,
                                                 int* __restrict__ fill, int* __restrict__ perm) {
  int e = blockIdx.x * 256 + threadIdx.x;
  if (e >= NE) return;
  int d = dst[e];
  int p = atomicAdd(&fill[d], 1);
  perm[row_start[d] + p] = e;
}

// ---------------- graph ranges (batch is sorted)
__global__ __launch_bounds__(256) void k_gstart(const int* __restrict__ batch, int* __restrict__ gs) {
  int i = blockIdx.x * 256 + threadIdx.x;
  if (i >= NN) return;
  int b = batch[i];
  if (i == 0) {
    for (int g = 0; g <= b; ++g) gs[g] = 0;
  } else {
    int pb = batch[i - 1];
    for (int g = pb + 1; g <= b; ++g) gs[g] = i;
  }
  if (i == NN - 1) {
    for (int g = b + 1; g <= NG; ++g) gs[g] = NN;
  }
}

// ---------------- conv GEMM: out[n,0:128] = X[n,0:DIN] @ W[DIN,128]
template <int DIN>
__global__ __launch_bounds__(256) void k_gemm_conv(const float* __restrict__ X, const float* __restrict__ W,
                                                   float* __restrict__ out) {
  __shared__ float Xs[32][132];
  __shared__ float Ws[32][128];
  int t = threadIdx.x;
  int n0 = blockIdx.x * 128;
  int tj = t & 15, tn = t >> 4;
  float acc[8][8];
#pragma unroll
  for (int a = 0; a < 8; ++a)
#pragma unroll
    for (int b = 0; b < 8; ++b) acc[a][b] = 0.f;

  for (int k0 = 0; k0 < DIN; k0 += 32) {
    __syncthreads();
#pragma unroll
    for (int i = 0; i < 16; ++i) {
      int q = t + 256 * i;
      int r = q & 31, row = q >> 5;
      int gn = n0 + row;
      Xs[r][row] = (gn < NN) ? X[(size_t)gn * DIN + k0 + r] : 0.f;
    }
#pragma unroll
    for (int i = 0; i < 16; ++i) {
      int q = t + 256 * i;
      int r = q >> 7, j = q & 127;
      Ws[r][j] = W[(k0 + r) * HC + j];
    }
    __syncthreads();
#pragma unroll
    for (int r = 0; r < 32; ++r) {
      float4 xa = *(const float4*)&Xs[r][tn * 8];
      float4 xb = *(const float4*)&Xs[r][tn * 8 + 4];
      float4 wa = *(const float4*)&Ws[r][tj * 8];
      float4 wb = *(const float4*)&Ws[r][tj * 8 + 4];
      float xr[8] = {xa.x, xa.y, xa.z, xa.w, xb.x, xb.y, xb.z, xb.w};
      float wr[8] = {wa.x, wa.y, wa.z, wa.w, wb.x, wb.y, wb.z, wb.w};
#pragma unroll
      for (int a = 0; a < 8; ++a)
#pragma unroll
        for (int b = 0; b < 8; ++b) acc[a][b] += xr[a] * wr[b];
    }
  }
#pragma unroll
  for (int a = 0; a < 8; ++a) {
    int n = n0 + tn * 8 + a;
    if (n < NN) {
      float4 v0 = make_float4(acc[a][0], acc[a][1], acc[a][2], acc[a][3]);
      float4 v1 = make_float4(acc[a][4], acc[a][5], acc[a][6], acc[a][7]);
      *(float4*)&out[(size_t)n * HC + tj * 8] = v0;
      *(float4*)&out[(size_t)n * HC + tj * 8 + 4] = v1;
    }
  }
}

// ---------------- per-node attention dots
__global__ __launch_bounds__(256) void k_attn_node(const float* __restrict__ ht, const float* __restrict__ a_s,
                                                   const float* __restrict__ a_d, float* __restrict__ asrc,
                                                   float* __restrict__ adst) {
  __shared__ float ss[HC], sd[HC];
  int t = threadIdx.x;
  if (t < HC) {
    ss[t] = a_s[t];
    sd[t] = a_d[t];
  }
  __syncthreads();
  int p = blockIdx.x * 256 + t;
  if (p >= NN * NHEAD) return;
  int n = p >> 2, h = p & 3;
  const float* hrow = &ht[(size_t)n * HC + h * CH];
  float sa = 0.f, da = 0.f;
#pragma unroll
  for (int k = 0; k < CH; k += 4) {
    float4 hv = *(const float4*)&hrow[k];
    float4 av = *(const float4*)&ss[h * CH + k];
    float4 dv = *(const float4*)&sd[h * CH + k];
    sa += hv.x * av.x + hv.y * av.y + hv.z * av.z + hv.w * av.w;
    da += hv.x * dv.x + hv.y * dv.y + hv.z * dv.z + hv.w * dv.w;
  }
  asrc[p] = sa;
  adst[p] = da;
}

// ---------------- per-edge exp(leaky(...))
__global__ __launch_bounds__(256) void k_alpha(const int* __restrict__ src, const int* __restrict__ dst,
                                               const float* __restrict__ edge_attr, const float* __restrict__ wea,
                                               const float* __restrict__ asrc, const float* __restrict__ adst,
                                               float* __restrict__ exbuf) {
  __shared__ float wl[EDIM * NHEAD];
  int t = threadIdx.x;
  if (t < EDIM * NHEAD) wl[t] = wea[t];
  __syncthreads();
  int e = blockIdx.x * 256 + t;
  if (e >= NE) return;
  int s = src[e], d = dst[e];
  float4 as4 = *(const float4*)&asrc[s * 4];
  float4 ad4 = *(const float4*)&adst[d * 4];
  float ae[4] = {0.f, 0.f, 0.f, 0.f};
#pragma unroll
  for (int k = 0; k < EDIM; ++k) {
    float ev = edge_attr[(size_t)e * EDIM + k];
    ae[0] += ev * wl[k * 4 + 0];
    ae[1] += ev * wl[k * 4 + 1];
    ae[2] += ev * wl[k * 4 + 2];
    ae[3] += ev * wl[k * 4 + 3];
  }
  float4 o;
  o.x = __expf(lrelu(as4.x + ad4.x + ae[0], 0.2f));
  o.y = __expf(lrelu(as4.y + ad4.y + ae[1], 0.2f));
  o.z = __expf(lrelu(as4.z + ad4.z + ae[2], 0.2f));
  o.w = __expf(lrelu(as4.w + ad4.w + ae[3], 0.2f));
  *(float4*)&exbuf[e * 4] = o;
}

// ---------------- aggregation: one wave per node; also writes bf16 shadow column block of Xb
__global__ __launch_bounds__(256) void k_aggregate(const float* __restrict__ ht, const float* __restrict__ exbuf,
                                                   const int* __restrict__ row_start, const int* __restrict__ perm,
                                                   const int* __restrict__ src, const float* __restrict__ bias,
                                                   float* __restrict__ hout, unsigned short* __restrict__ xb,
                                                   int col0) {
  int t = threadIdx.x;
  int lane = t & 63;
  int n = blockIdx.x * 4 + (t >> 6);
  if (n >= NN) return;
  int rs = row_start[n], re = row_start[n + 1];
  float d0 = 0.f, d1 = 0.f, d2 = 0.f, d3 = 0.f;
  for (int i = rs + lane; i < re; i += 64) {
    int e = perm[i];
    float4 ex = *(const float4*)&exbuf[e * 4];
    d0 += ex.x; d1 += ex.y; d2 += ex.z; d3 += ex.w;
  }
#pragma unroll
  for (int m = 1; m < 64; m <<= 1) {
    d0 += __shfl_xor(d0, m, 64);
    d1 += __shfl_xor(d1, m, 64);
    d2 += __shfl_xor(d2, m, 64);
    d3 += __shfl_xor(d3, m, 64);
  }
  float inv0 = 1.f / (d0 + 1e-16f), inv1 = 1.f / (d1 + 1e-16f);
  float inv2 = 1.f / (d2 + 1e-16f), inv3 = 1.f / (d3 + 1e-16f);
  int c0 = lane, c1 = lane + 64;
  int h0 = lane >> 5, h1 = 2 + (lane >> 5);
  float acc0 = 0.f, acc1 = 0.f;
  for (int i = rs; i < re; ++i) {
    int e = perm[i];
    int s = src[e];
    float e0 = exbuf[e * 4 + h0];
    float e1 = exbuf[e * 4 + h1];
    acc0 += e0 * ht[(size_t)s * HC + c0];
    acc1 += e1 * ht[(size_t)s * HC + c1];
  }
  float iv0 = (h0 == 0) ? inv0 : inv1;
  float iv1 = (h1 == 2) ? inv2 : inv3;
  float vo0 = acc0 * iv0 + bias[c0];
  float vo1 = acc1 * iv1 + bias[c1];
  hout[(size_t)n * HC + c0] = vo0;
  hout[(size_t)n * HC + c1] = vo1;
  xb[(size_t)n * 384 + col0 + c0] = f2bf(vo0);
  xb[(size_t)n * 384 + col0 + c1] = f2bf(vo1);
}

// ---------------- global add pool
__global__ __launch_bounds__(128) void k_pool(const float* __restrict__ h3, const int* __restrict__ gs,
                                              float* __restrict__ hpool) {
  int g = blockIdx.x;
  int j = threadIdx.x;
  int s = gs[g], e = gs[g + 1];
  float acc = 0.f;
  for (int i = s; i < e; ++i) acc += h3[(size_t)i * HC + j];
  hpool[(size_t)g * HC + j] = acc;
}

// ---------------- ph[g,0:512] = hpool[g,0:128] @ lw1[384:512, 0:512]
__global__ __launch_bounds__(256) void k_pool_gemm(const float* __restrict__ hpool, const float* __restrict__ lw1,
                                                   float* __restrict__ ph) {
  __shared__ float hp[16][128];
  int t = threadIdx.x;
  int j0 = blockIdx.x * 128;
  int g0 = blockIdx.y * 16;
  int jj = t & 127, gg = t >> 7;
#pragma unroll
  for (int i = 0; i < 8; ++i) {
    int q = t + 256 * i;
    int row = q >> 7, col = q & 127;
    hp[row][col] = hpool[(size_t)(g0 + row) * HC + col];
  }
  __syncthreads();
  float acc[8];
#pragma unroll
  for (int i = 0; i < 8; ++i) acc[i] = 0.f;
  for (int k = 0; k < HC; ++k) {
    float wv = lw1[(size_t)(384 + k) * 512 + j0 + jj];
#pragma unroll
    for (int gi = 0; gi < 8; ++gi) acc[gi] += hp[gg + 2 * gi][k] * wv;
  }
#pragma unroll
  for (int gi = 0; gi < 8; ++gi) ph[(size_t)(g0 + gg + 2 * gi) * 512 + j0 + jj] = acc[gi];
}

__global__ __launch_bounds__(256) void k_outinit(float* __restrict__ out, const float* __restrict__ lb2) {
  int i = blockIdx.x * 256 + threadIdx.x;
  if (i < NN) out[i] = lb2[0];
}

// ---------------- fused MLP via bf16 MFMA:
// hidden = leaky(Xb@lw1[0:384] + ph[batch] + lb1, .01); out += hidden@lw2
// 128x128 tile, 4 waves each 64x64 (4x4 of 16x16x32 MFMA).
__global__ __launch_bounds__(256) void k_mlp_mfma(
    const unsigned short* __restrict__ xb, const unsigned short* __restrict__ lw1tb,
    const float* __restrict__ ph, const int* __restrict__ batch,
    const float* __restrict__ lb1, const float* __restrict__ lw2,
    float* __restrict__ out) {
  __shared__ unsigned short As[128 * SP];
  __shared__ unsigned short Bs[128 * SP];
  int t = threadIdx.x;
  int j0 = blockIdx.x * 128;   // 4 j-tiles (fast dim -> consecutive blocks share A rows in L2)
  int n0 = blockIdx.y * 128;   // 391 m-tiles
  int lane = t & 63;
  int wave = t >> 6;
  int wr = wave >> 1, wc = wave & 1;

  floatx4 acc[4][4];
#pragma unroll
  for (int a = 0; a < 4; ++a)
#pragma unroll
    for (int b = 0; b < 4; ++b) acc[a][b] = (floatx4){0.f, 0.f, 0.f, 0.f};

  // staging assignment: row-per-thread keeps ds_write banks on the free 8-row cycle
  int sm = t & 127;            // tile row
  int sc = (t >> 7) * 16;      // k-chunk base: 0 or 16
  bool arow_ok = (n0 + sm) < NN;
  const unsigned short* aglob = xb + (size_t)(n0 + sm) * 384 + sc;
  const unsigned short* bglob = lw1tb + (size_t)(j0 + sm) * 384 + sc;
  unsigned short* asl = As + sm * SP + sc;
  unsigned short* bsl = Bs + sm * SP + sc;

  int frow = lane & 15, fk = (lane >> 4) * 8;
  const unsigned short* arow = As + (wr * 64 + frow) * SP + fk;
  const unsigned short* brow = Bs + (wc * 64 + frow) * SP + fk;

  for (int k0 = 0; k0 < 384; k0 += 32) {
    uint4 a0 = arow_ok ? *(const uint4*)(aglob) : make_uint4(0, 0, 0, 0);
    uint4 a1 = arow_ok ? *(const uint4*)(aglob + 8) : make_uint4(0, 0, 0, 0);
    uint4 b0 = *(const uint4*)(bglob);
    uint4 b1 = *(const uint4*)(bglob + 8);
    aglob += 32;
    bglob += 32;
    __syncthreads();  // previous iter's frag reads complete
    *(uint4*)(asl) = a0;
    *(uint4*)(asl + 8) = a1;
    *(uint4*)(bsl) = b0;
    *(uint4*)(bsl + 8) = b1;
    __syncthreads();
    short8 af[4], bf[4];
#pragma unroll
    for (int ti = 0; ti < 4; ++ti) af[ti] = *(const short8*)(arow + ti * 16 * SP);
#pragma unroll
    for (int tj = 0; tj < 4; ++tj) bf[tj] = *(const short8*)(brow + tj * 16 * SP);
#pragma unroll
    for (int ti = 0; ti < 4; ++ti)
#pragma unroll
      for (int tj = 0; tj < 4; ++tj)
        acc[ti][tj] = __builtin_amdgcn_mfma_f32_16x16x32_bf16(af[ti], bf[tj], acc[ti][tj], 0, 0, 0);
  }

  // epilogue: D[row][col]: row=(lane>>4)*4+r, col=lane&15 within each 16x16 tile
  int colg = j0 + wc * 64 + (lane & 15);
#pragma unroll
  for (int ti = 0; ti < 4; ++ti) {
    int rowb = n0 + wr * 64 + ti * 16 + (lane >> 4) * 4;
#pragma unroll
    for (int r = 0; r < 4; ++r) {
      int row = rowb + r;
      int rc = (row < NN) ? row : 0;
      int bg = batch[rc];
      float partial = 0.f;
#pragma unroll
      for (int tj = 0; tj < 4; ++tj) {
        int j = colg + tj * 16;
        float v = acc[ti][tj][r] + ph[(size_t)bg * 512 + j] + lb1[j];
        partial += lrelu(v, 0.01f) * lw2[j];
      }
#pragma unroll
      for (int m = 1; m < 16; m <<= 1) partial += __shfl_xor(partial, m, 16);
      if ((lane & 15) == 0 && row < NN) atomicAdd(&out[row], partial);
    }
  }
}

extern "C" void kernel_launch(void* const* d_in, const int* in_sizes, int n_in,
                              void* d_out, int out_size, void* d_ws, size_t ws_size,
                              hipStream_t stream) {
  const float* x = (const float*)d_in[0];
  const int* edge_index = (const int*)d_in[1];
  const int* src = edge_index;
  const int* dstp = edge_index + NE;
  const float* edge_attr = (const float*)d_in[2];
  const int* batch = (const int*)d_in[3];
  const float* W[3] = {(const float*)d_in[4], (const float*)d_in[10], (const float*)d_in[16]};
  const float* as_[3] = {(const float*)d_in[5], (const float*)d_in[11], (const float*)d_in[17]};
  const float* ad_[3] = {(const float*)d_in[6], (const float*)d_in[12], (const float*)d_in[18]};
  const float* We_[3] = {(const float*)d_in[7], (const float*)d_in[13], (const float*)d_in[19]};
  const float* ae_[3] = {(const float*)d_in[8], (const float*)d_in[14], (const float*)d_in[20]};
  const float* b_[3] = {(const float*)d_in[9], (const float*)d_in[15], (const float*)d_in[21]};
  const float* lw1 = (const float*)d_in[22];
  const float* lb1 = (const float*)d_in[23];
  const float* lw2 = (const float*)d_in[24];
  const float* lb2 = (const float*)d_in[25];
  float* out = (float*)d_out;

  // workspace carve-up (floats unless noted)
  float* f = (float*)d_ws;
  size_t o = 0;
  float* ht = f + o;    o += (size_t)NN * HC;       // conv output (pre-attention), reused per layer
  float* hagg = f + o;  o += (size_t)NN * HC;       // aggregate output fp32, reused per layer
  float* asrc = f + o;  o += (size_t)NN * NHEAD;
  float* adst = f + o;  o += (size_t)NN * NHEAD;
  float* exbuf = f + o; o += (size_t)NE * NHEAD;
  float* wea = f + o;   o += 256;
  float* hpool = f + o; o += (size_t)NG * HC;
  float* ph = f + o;    o += (size_t)NG * 512;
  unsigned short* xb = (unsigned short*)(f + o);    o += (size_t)NN * 384 / 2;  // bf16 [N,384]
  unsigned short* lw1tb = (unsigned short*)(f + o); o += (512 * 384) / 2;       // bf16 [512][384]
  int* row_start = (int*)(f + o);
  int* cnt = row_start + (NN + 1);
  int* fill = cnt + NN;
  int* aux = fill + NN;
  int* gs = aux + 256;
  int* perm = gs + (NG + 1);

  const int NB = (NN + 255) / 256;
  const int EB = (NE + 255) / 256;

  hipMemsetAsync(cnt, 0, (size_t)2 * NN * sizeof(int), stream);  // cnt + fill

  k_we_a<<<1, 256, 0, stream>>>(We_[0], ae_[0], We_[1], ae_[1], We_[2], ae_[2], wea);
  k_lw1t<<<(512 * 384 + 255) / 256, 256, 0, stream>>>(lw1, lw1tb);
  k_hist<<<EB, 256, 0, stream>>>(dstp, cnt);
  k_scan1<<<NB, 256, 0, stream>>>(cnt, row_start, aux);
  k_scan2<<<1, 256, 0, stream>>>(aux, NB);
  k_scan3<<<NB, 256, 0, stream>>>(row_start, aux);
  k_scatter<<<EB, 256, 0, stream>>>(dstp, row_start, fill, perm);
  k_gstart<<<NB, 256, 0, stream>>>(batch, gs);
  k_outinit<<<NB, 256, 0, stream>>>(out, lb2);

  for (int l = 0; l < 3; ++l) {
    const float* xin = (l == 0) ? x : hagg;
    if (l == 0)
      k_gemm_conv<DIN1><<<(NN + 127) / 128, 256, 0, stream>>>(xin, W[l], ht);
    else
      k_gemm_conv<HC><<<(NN + 127) / 128, 256, 0, stream>>>(xin, W[l], ht);
    k_attn_node<<<(NN * NHEAD + 255) / 256, 256, 0, stream>>>(ht, as_[l], ad_[l], asrc, adst);
    k_alpha<<<EB, 256, 0, stream>>>(src, dstp, edge_attr, wea + l * 64, asrc, adst, exbuf);
    k_aggregate<<<(NN + 3) / 4, 256, 0, stream>>>(ht, exbuf, row_start, perm, src, b_[l], hagg, xb, l * HC);
  }

  k_pool<<<NG, 128, 0, stream>>>(hagg, gs, hpool);
  k_pool_gemm<<<dim3(4, NG / 16), 256, 0, stream>>>(hpool, lw1, ph);
  k_mlp_mfma<<<dim3(4, (NN + 127) / 128), 256, 0, stream>>>(xb, lw1tb, ph, batch, lb1, lw2, out);
}

// Round 3
// 611.340 us; speedup vs baseline: 2.5858x; 1.6352x over previous
//
#include <hip/hip_runtime.h>
#include <hip/hip_bf16.h>
#include <math.h>

#define NN 50000
#define NE 800000
#define DIN1 64
#define NHEAD 4
#define CH 32
#define HC 128
#define EDIM 16
#define NG 2000
#define SP 56     // LDS k-stride in bf16 elems
#define MAXCH 64  // edge chunk per node-wave

typedef __attribute__((ext_vector_type(8))) short short8;
typedef __attribute__((ext_vector_type(4))) float floatx4;

__device__ __forceinline__ float lrelu(float x, float s) { return x > 0.f ? x : s * x; }

__device__ __forceinline__ unsigned short f2bf(float x) {
  unsigned int u = __float_as_uint(x);
  u += 0x7fff + ((u >> 16) & 1);  // RNE
  return (unsigned short)(u >> 16);
}
__device__ __forceinline__ float bflo(unsigned int u) { return __uint_as_float(u << 16); }
__device__ __forceinline__ float bfhi(unsigned int u) { return __uint_as_float(u & 0xffff0000u); }

// ---------------- we_a precompute: we_a[l*64 + d*4 + h] = sum_c We_l[d, h*32+c]*ae_l[h,c]
__global__ __launch_bounds__(256) void k_we_a(
    const float* __restrict__ We1, const float* __restrict__ ae1,
    const float* __restrict__ We2, const float* __restrict__ ae2,
    const float* __restrict__ We3, const float* __restrict__ ae3,
    float* __restrict__ we_a) {
  int t = threadIdx.x;
  if (t >= 3 * EDIM * NHEAD) return;
  int l = t / (EDIM * NHEAD);
  int rem = t % (EDIM * NHEAD);
  int d = rem / NHEAD, h = rem % NHEAD;
  const float* We = (l == 0) ? We1 : ((l == 1) ? We2 : We3);
  const float* ae = (l == 0) ? ae1 : ((l == 1) ? ae2 : ae3);
  float s = 0.f;
  for (int c = 0; c < CH; ++c) s += We[d * HC + h * CH + c] * ae[h * CH + c];
  we_a[t] = s;
}

// ---------------- lw1 rows 0:384 -> transposed bf16 [512][384]
__global__ __launch_bounds__(256) void k_lw1t(const float* __restrict__ lw1, unsigned short* __restrict__ lw1tb) {
  int i = blockIdx.x * 256 + threadIdx.x;
  if (i >= 512 * 384) return;
  int n = i / 384, k = i % 384;
  lw1tb[i] = f2bf(lw1[(size_t)k * 512 + n]);
}

// ---------------- W1/W2/W3 -> transposed bf16: wt1[128][64], wt2[128][128], wt3[128][128]
__global__ __launch_bounds__(256) void k_wt(const float* __restrict__ W1, const float* __restrict__ W2,
                                            const float* __restrict__ W3, unsigned short* __restrict__ wtb) {
  int i = blockIdx.x * 256 + threadIdx.x;
  if (i < 128 * 64) {
    int j = i / 64, k = i % 64;
    wtb[i] = f2bf(W1[k * HC + j]);
  } else if (i < 128 * 64 + 128 * 128) {
    int ii = i - 128 * 64;
    int j = ii / 128, k = ii % 128;
    wtb[i] = f2bf(W2[k * HC + j]);
  } else if (i < 128 * 64 + 2 * 128 * 128) {
    int ii = i - (128 * 64 + 128 * 128);
    int j = ii / 128, k = ii % 128;
    wtb[i] = f2bf(W3[k * HC + j]);
  }
}

// ---------------- cast x fp32 -> bf16
__global__ __launch_bounds__(256) void k_cast(const float* __restrict__ x, unsigned short* __restrict__ xb0) {
  int i = blockIdx.x * 256 + threadIdx.x;
  if (i < NN * DIN1) xb0[i] = f2bf(x[i]);
}

// ---------------- CSR build
__global__ __launch_bounds__(256) void k_hist(const int* __restrict__ dst, int* __restrict__ cnt) {
  int e = blockIdx.x * 256 + threadIdx.x;
  if (e < NE) atomicAdd(&cnt[dst[e]], 1);
}

__global__ __launch_bounds__(256) void k_scan1(const int* __restrict__ cnt, int* __restrict__ row_start,
                                               int* __restrict__ aux) {
  __shared__ int s[256];
  int t = threadIdx.x;
  int i = blockIdx.x * 256 + t;
  int v = (i < NN) ? cnt[i] : 0;
  s[t] = v;
  __syncthreads();
  for (int off = 1; off < 256; off <<= 1) {
    int tv = (t >= off) ? s[t - off] : 0;
    __syncthreads();
    s[t] += tv;
    __syncthreads();
  }
  if (i < NN) row_start[i] = s[t] - v;
  if (t == 255) aux[blockIdx.x] = s[255];
}

__global__ __launch_bounds__(256) void k_scan2(int* __restrict__ aux, int nb) {
  __shared__ int s[256];
  int t = threadIdx.x;
  int v = (t < nb) ? aux[t] : 0;
  s[t] = v;
  __syncthreads();
  for (int off = 1; off < 256; off <<= 1) {
    int tv = (t >= off) ? s[t - off] : 0;
    __syncthreads();
    s[t] += tv;
    __syncthreads();
  }
  if (t < nb) aux[t] = s[t] - v;
}

__global__ __launch_bounds__(256) void k_scan3(int* __restrict__ row_start, const int* __restrict__ aux) {
  int i = blockIdx.x * 256 + threadIdx.x;
  if (i < NN) row_start[i] += aux[i >> 8];
  else if (i == NN) row_start[NN] = NE;
}

// ---------------- scatter: permute src + per-layer edge logits into CSR order
__global__ __launch_bounds__(256) void k_scatter(const int* __restrict__ src, const int* __restrict__ dst,
                                                 const float* __restrict__ edge_attr, const float* __restrict__ wea,
                                                 const int* __restrict__ row_start, int* __restrict__ fill,
                                                 int* __restrict__ srcp, float* __restrict__ aep) {
  __shared__ float wl[3 * EDIM * NHEAD];
  int t = threadIdx.x;
  if (t < 3 * EDIM * NHEAD) wl[t] = wea[t];
  __syncthreads();
  int e = blockIdx.x * 256 + t;
  if (e >= NE) return;
  int d = dst[e];
  int p = atomicAdd(&fill[d], 1);
  int pos = row_start[d] + p;
  srcp[pos] = src[e];
  float ea[EDIM];
#pragma unroll
  for (int k = 0; k < EDIM; k += 4) {
    float4 v = *(const float4*)&edge_attr[(size_t)e * EDIM + k];
    ea[k] = v.x; ea[k + 1] = v.y; ea[k + 2] = v.z; ea[k + 3] = v.w;
  }
#pragma unroll
  for (int l = 0; l < 3; ++l) {
    float a0 = 0.f, a1 = 0.f, a2 = 0.f, a3 = 0.f;
#pragma unroll
    for (int k = 0; k < EDIM; ++k) {
      float ev = ea[k];
      a0 += ev * wl[l * 64 + k * 4 + 0];
      a1 += ev * wl[l * 64 + k * 4 + 1];
      a2 += ev * wl[l * 64 + k * 4 + 2];
      a3 += ev * wl[l * 64 + k * 4 + 3];
    }
    *(float4*)&aep[(size_t)l * NE * 4 + (size_t)pos * 4] = make_float4(a0, a1, a2, a3);
  }
}

// ---------------- graph ranges (batch is sorted)
__global__ __launch_bounds__(256) void k_gstart(const int* __restrict__ batch, int* __restrict__ gs) {
  int i = blockIdx.x * 256 + threadIdx.x;
  if (i >= NN) return;
  int b = batch[i];
  if (i == 0) {
    for (int g = 0; g <= b; ++g) gs[g] = 0;
  } else {
    int pb = batch[i - 1];
    for (int g = pb + 1; g <= b; ++g) gs[g] = i;
  }
  if (i == NN - 1) {
    for (int g = b + 1; g <= NG; ++g) gs[g] = NN;
  }
}

// ---------------- conv GEMM via MFMA: htb[n,0:128] = bf16( Xb[n,0:K] @ Wt^T )
template <int K, int ASTRIDE>
__global__ __launch_bounds__(256) void k_conv_mfma(const unsigned short* __restrict__ xin,
                                                   const unsigned short* __restrict__ wt,
                                                   unsigned short* __restrict__ htb) {
  __shared__ unsigned short As[128 * SP];
  __shared__ unsigned short Bs[128 * SP];
  int t = threadIdx.x;
  int n0 = blockIdx.x * 128;
  int lane = t & 63;
  int wave = t >> 6;
  int wr = wave >> 1, wc = wave & 1;

  floatx4 acc[4][4];
#pragma unroll
  for (int a = 0; a < 4; ++a)
#pragma unroll
    for (int b = 0; b < 4; ++b) acc[a][b] = (floatx4){0.f, 0.f, 0.f, 0.f};

  int sm = t & 127;
  int sc = (t >> 7) * 16;
  bool arow_ok = (n0 + sm) < NN;
  const unsigned short* aglob = xin + (size_t)(n0 + sm) * ASTRIDE + sc;
  const unsigned short* bglob = wt + sm * K + sc;
  unsigned short* asl = As + sm * SP + sc;
  unsigned short* bsl = Bs + sm * SP + sc;

  int frow = lane & 15, fk = (lane >> 4) * 8;
  const unsigned short* arow = As + (wr * 64 + frow) * SP + fk;
  const unsigned short* brow = Bs + (wc * 64 + frow) * SP + fk;

  for (int k0 = 0; k0 < K; k0 += 32) {
    uint4 a0 = arow_ok ? *(const uint4*)(aglob) : make_uint4(0, 0, 0, 0);
    uint4 a1 = arow_ok ? *(const uint4*)(aglob + 8) : make_uint4(0, 0, 0, 0);
    uint4 b0 = *(const uint4*)(bglob);
    uint4 b1 = *(const uint4*)(bglob + 8);
    aglob += 32;
    bglob += 32;
    __syncthreads();
    *(uint4*)(asl) = a0;
    *(uint4*)(asl + 8) = a1;
    *(uint4*)(bsl) = b0;
    *(uint4*)(bsl + 8) = b1;
    __syncthreads();
    short8 af[4], bf[4];
#pragma unroll
    for (int ti = 0; ti < 4; ++ti) af[ti] = *(const short8*)(arow + ti * 16 * SP);
#pragma unroll
    for (int tj = 0; tj < 4; ++tj) bf[tj] = *(const short8*)(brow + tj * 16 * SP);
#pragma unroll
    for (int ti = 0; ti < 4; ++ti)
#pragma unroll
      for (int tj = 0; tj < 4; ++tj)
        acc[ti][tj] = __builtin_amdgcn_mfma_f32_16x16x32_bf16(af[ti], bf[tj], acc[ti][tj], 0, 0, 0);
  }

  int colg = wc * 64 + (lane & 15);
#pragma unroll
  for (int ti = 0; ti < 4; ++ti) {
    int rowb = n0 + wr * 64 + ti * 16 + (lane >> 4) * 4;
#pragma unroll
    for (int r = 0; r < 4; ++r) {
      int row = rowb + r;
      if (row < NN) {
#pragma unroll
        for (int tj = 0; tj < 4; ++tj) htb[(size_t)row * HC + colg + tj * 16] = f2bf(acc[ti][tj][r]);
      }
    }
  }
}

// ---------------- per-node attention dots (bf16 input)
__global__ __launch_bounds__(256) void k_attn_node(const unsigned short* __restrict__ htb,
                                                   const float* __restrict__ a_s, const float* __restrict__ a_d,
                                                   float* __restrict__ asrc, float* __restrict__ adst) {
  __shared__ float ss[HC], sd[HC];
  int t = threadIdx.x;
  if (t < HC) {
    ss[t] = a_s[t];
    sd[t] = a_d[t];
  }
  __syncthreads();
  int p = blockIdx.x * 256 + t;
  if (p >= NN * NHEAD) return;
  int n = p >> 2, h = p & 3;
  const unsigned short* hrow = htb + (size_t)n * HC + h * CH;
  float sa = 0.f, da = 0.f;
#pragma unroll
  for (int k = 0; k < CH; k += 8) {
    uint4 u = *(const uint4*)(hrow + k);
    float hv[8] = {bflo(u.x), bfhi(u.x), bflo(u.y), bfhi(u.y), bflo(u.z), bfhi(u.z), bflo(u.w), bfhi(u.w)};
#pragma unroll
    for (int j = 0; j < 8; ++j) {
      sa += hv[j] * ss[h * CH + k + j];
      da += hv[j] * sd[h * CH + k + j];
    }
  }
  asrc[p] = sa;
  adst[p] = da;
}

// ---------------- fused alpha + softmax + aggregate. One wave per node.
// xb[n, col0+c] = bf16( (1/denom_h) * sum_e exp(leaky(asrc[s]+adst[n]+ae[e],.2))_h * htb[s,c] + bias[c] )
__global__ __launch_bounds__(256) void k_aggregate(
    const unsigned short* __restrict__ htb, const int* __restrict__ srcp,
    const float* __restrict__ aep, const float* __restrict__ asrc, const float* __restrict__ adst,
    const int* __restrict__ row_start, const float* __restrict__ bias,
    unsigned short* __restrict__ xb, int col0) {
  __shared__ float exs[4][MAXCH][4];
  __shared__ int cns[4];
  int t = threadIdx.x;
  int lane = t & 63, wid = t >> 6;
  int n = blockIdx.x * 4 + wid;
  bool nok = n < NN;
  int rs = nok ? row_start[n] : 0;
  int re = nok ? row_start[n + 1] : 0;
  int deg = re - rs;
  if (lane == 0) cns[wid] = (deg + MAXCH - 1) / MAXCH;
  __syncthreads();
  int maxc = max(max(cns[0], cns[1]), max(cns[2], cns[3]));
  int q = lane & 15, g = lane >> 4;
  int h = q >> 2;
  float4 ad4 = nok ? *(const float4*)&adst[n * 4] : make_float4(0.f, 0.f, 0.f, 0.f);
  float acc[8];
#pragma unroll
  for (int j = 0; j < 8; ++j) acc[j] = 0.f;
  float d0 = 0.f, d1 = 0.f, d2 = 0.f, d3 = 0.f;

  for (int cc = 0; cc < maxc; ++cc) {
    int base = rs + cc * MAXCH;
    int m = re - base;
    if (m > MAXCH) m = MAXCH;
    if (lane < m) {
      int i = base + lane;
      int s = srcp[i];
      float4 ae = *(const float4*)&aep[(size_t)i * 4];
      float4 as4 = *(const float4*)&asrc[s * 4];
      float4 ex;
      ex.x = __expf(lrelu(as4.x + ad4.x + ae.x, 0.2f));
      ex.y = __expf(lrelu(as4.y + ad4.y + ae.y, 0.2f));
      ex.z = __expf(lrelu(as4.z + ad4.z + ae.z, 0.2f));
      ex.w = __expf(lrelu(as4.w + ad4.w + ae.w, 0.2f));
      *(float4*)&exs[wid][lane][0] = ex;
      d0 += ex.x; d1 += ex.y; d2 += ex.z; d3 += ex.w;
    }
    __syncthreads();
    int iters = (m > 0) ? ((m + 3) >> 2) : 0;
    for (int kk = 0; kk < iters; ++kk) {
      int ii = kk * 4 + g;
      if (ii < m) {
        int i = base + ii;
        int s = srcp[i];
        float w = exs[wid][ii][h];
        uint4 hv = *(const uint4*)(htb + (size_t)s * HC + q * 8);
        acc[0] += w * bflo(hv.x);
        acc[1] += w * bfhi(hv.x);
        acc[2] += w * bflo(hv.y);
        acc[3] += w * bfhi(hv.y);
        acc[4] += w * bflo(hv.z);
        acc[5] += w * bfhi(hv.z);
        acc[6] += w * bflo(hv.w);
        acc[7] += w * bfhi(hv.w);
      }
    }
    __syncthreads();
  }

#pragma unroll
  for (int mm = 1; mm < 64; mm <<= 1) {
    d0 += __shfl_xor(d0, mm, 64);
    d1 += __shfl_xor(d1, mm, 64);
    d2 += __shfl_xor(d2, mm, 64);
    d3 += __shfl_xor(d3, mm, 64);
  }
#pragma unroll
  for (int j = 0; j < 8; ++j) {
    acc[j] += __shfl_xor(acc[j], 16, 64);
    acc[j] += __shfl_xor(acc[j], 32, 64);
  }
  if (nok && g == 0) {
    float dh = (h == 0) ? d0 : ((h == 1) ? d1 : ((h == 2) ? d2 : d3));
    float inv = 1.f / (dh + 1e-16f);
    unsigned int w[4];
#pragma unroll
    for (int j = 0; j < 4; ++j) {
      float v0 = acc[2 * j] * inv + bias[q * 8 + 2 * j];
      float v1 = acc[2 * j + 1] * inv + bias[q * 8 + 2 * j + 1];
      w[j] = (unsigned int)f2bf(v0) | ((unsigned int)f2bf(v1) << 16);
    }
    *(uint4*)&xb[(size_t)n * 384 + col0 + q * 8] = make_uint4(w[0], w[1], w[2], w[3]);
  }
}

// ---------------- global add pool from xb col slice 256:384 (= h3)
__global__ __launch_bounds__(128) void k_pool(const unsigned short* __restrict__ xb, const int* __restrict__ gs,
                                              float* __restrict__ hpool) {
  int g = blockIdx.x;
  int j = threadIdx.x;
  int s = gs[g], e = gs[g + 1];
  float acc = 0.f;
  for (int i = s; i < e; ++i) acc += bflo((unsigned int)xb[(size_t)i * 384 + 256 + j]);
  hpool[(size_t)g * HC + j] = acc;
}

// ---------------- ph[g,0:512] = hpool[g,0:128] @ lw1[384:512, 0:512]
__global__ __launch_bounds__(256) void k_pool_gemm(const float* __restrict__ hpool, const float* __restrict__ lw1,
                                                   float* __restrict__ ph) {
  __shared__ float hp[16][128];
  int t = threadIdx.x;
  int j0 = blockIdx.x * 128;
  int g0 = blockIdx.y * 16;
  int jj = t & 127, gg = t >> 7;
#pragma unroll
  for (int i = 0; i < 8; ++i) {
    int q = t + 256 * i;
    int row = q >> 7, col = q & 127;
    hp[row][col] = hpool[(size_t)(g0 + row) * HC + col];
  }
  __syncthreads();
  float acc[8];
#pragma unroll
  for (int i = 0; i < 8; ++i) acc[i] = 0.f;
  for (int k = 0; k < HC; ++k) {
    float wv = lw1[(size_t)(384 + k) * 512 + j0 + jj];
#pragma unroll
    for (int gi = 0; gi < 8; ++gi) acc[gi] += hp[gg + 2 * gi][k] * wv;
  }
#pragma unroll
  for (int gi = 0; gi < 8; ++gi) ph[(size_t)(g0 + gg + 2 * gi) * 512 + j0 + jj] = acc[gi];
}

__global__ __launch_bounds__(256) void k_outinit(float* __restrict__ out, const float* __restrict__ lb2) {
  int i = blockIdx.x * 256 + threadIdx.x;
  if (i < NN) out[i] = lb2[0];
}

// ---------------- fused MLP via bf16 MFMA (unchanged from round 2)
__global__ __launch_bounds__(256) void k_mlp_mfma(
    const unsigned short* __restrict__ xb, const unsigned short* __restrict__ lw1tb,
    const float* __restrict__ ph, const int* __restrict__ batch,
    const float* __restrict__ lb1, const float* __restrict__ lw2,
    float* __restrict__ out) {
  __shared__ unsigned short As[128 * SP];
  __shared__ unsigned short Bs[128 * SP];
  int t = threadIdx.x;
  int j0 = blockIdx.x * 128;
  int n0 = blockIdx.y * 128;
  int lane = t & 63;
  int wave = t >> 6;
  int wr = wave >> 1, wc = wave & 1;

  floatx4 acc[4][4];
#pragma unroll
  for (int a = 0; a < 4; ++a)
#pragma unroll
    for (int b = 0; b < 4; ++b) acc[a][b] = (floatx4){0.f, 0.f, 0.f, 0.f};

  int sm = t & 127;
  int sc = (t >> 7) * 16;
  bool arow_ok = (n0 + sm) < NN;
  const unsigned short* aglob = xb + (size_t)(n0 + sm) * 384 + sc;
  const unsigned short* bglob = lw1tb + (size_t)(j0 + sm) * 384 + sc;
  unsigned short* asl = As + sm * SP + sc;
  unsigned short* bsl = Bs + sm * SP + sc;

  int frow = lane & 15, fk = (lane >> 4) * 8;
  const unsigned short* arow = As + (wr * 64 + frow) * SP + fk;
  const unsigned short* brow = Bs + (wc * 64 + frow) * SP + fk;

  for (int k0 = 0; k0 < 384; k0 += 32) {
    uint4 a0 = arow_ok ? *(const uint4*)(aglob) : make_uint4(0, 0, 0, 0);
    uint4 a1 = arow_ok ? *(const uint4*)(aglob + 8) : make_uint4(0, 0, 0, 0);
    uint4 b0 = *(const uint4*)(bglob);
    uint4 b1 = *(const uint4*)(bglob + 8);
    aglob += 32;
    bglob += 32;
    __syncthreads();
    *(uint4*)(asl) = a0;
    *(uint4*)(asl + 8) = a1;
    *(uint4*)(bsl) = b0;
    *(uint4*)(bsl + 8) = b1;
    __syncthreads();
    short8 af[4], bf[4];
#pragma unroll
    for (int ti = 0; ti < 4; ++ti) af[ti] = *(const short8*)(arow + ti * 16 * SP);
#pragma unroll
    for (int tj = 0; tj < 4; ++tj) bf[tj] = *(const short8*)(brow + tj * 16 * SP);
#pragma unroll
    for (int ti = 0; ti < 4; ++ti)
#pragma unroll
      for (int tj = 0; tj < 4; ++tj)
        acc[ti][tj] = __builtin_amdgcn_mfma_f32_16x16x32_bf16(af[ti], bf[tj], acc[ti][tj], 0, 0, 0);
  }

  int colg = j0 + wc * 64 + (lane & 15);
#pragma unroll
  for (int ti = 0; ti < 4; ++ti) {
    int rowb = n0 + wr * 64 + ti * 16 + (lane >> 4) * 4;
#pragma unroll
    for (int r = 0; r < 4; ++r) {
      int row = rowb + r;
      int rc = (row < NN) ? row : 0;
      int bg = batch[rc];
      float partial = 0.f;
#pragma unroll
      for (int tj = 0; tj < 4; ++tj) {
        int j = colg + tj * 16;
        float v = acc[ti][tj][r] + ph[(size_t)bg * 512 + j] + lb1[j];
        partial += lrelu(v, 0.01f) * lw2[j];
      }
#pragma unroll
      for (int m = 1; m < 16; m <<= 1) partial += __shfl_xor(partial, m, 16);
      if ((lane & 15) == 0 && row < NN) atomicAdd(&out[row], partial);
    }
  }
}

extern "C" void kernel_launch(void* const* d_in, const int* in_sizes, int n_in,
                              void* d_out, int out_size, void* d_ws, size_t ws_size,
                              hipStream_t stream) {
  const float* x = (const float*)d_in[0];
  const int* edge_index = (const int*)d_in[1];
  const int* src = edge_index;
  const int* dstp = edge_index + NE;
  const float* edge_attr = (const float*)d_in[2];
  const int* batch = (const int*)d_in[3];
  const float* W[3] = {(const float*)d_in[4], (const float*)d_in[10], (const float*)d_in[16]};
  const float* as_[3] = {(const float*)d_in[5], (const float*)d_in[11], (const float*)d_in[17]};
  const float* ad_[3] = {(const float*)d_in[6], (const float*)d_in[12], (const float*)d_in[18]};
  const float* We_[3] = {(const float*)d_in[7], (const float*)d_in[13], (const float*)d_in[19]};
  const float* ae_[3] = {(const float*)d_in[8], (const float*)d_in[14], (const float*)d_in[20]};
  const float* b_[3] = {(const float*)d_in[9], (const float*)d_in[15], (const float*)d_in[21]};
  const float* lw1 = (const float*)d_in[22];
  const float* lb1 = (const float*)d_in[23];
  const float* lw2 = (const float*)d_in[24];
  const float* lb2 = (const float*)d_in[25];
  float* out = (float*)d_out;

  // workspace carve-up
  float* f = (float*)d_ws;
  size_t o = 0;  // in floats
  float* asrc = f + o;  o += (size_t)NN * NHEAD;
  float* adst = f + o;  o += (size_t)NN * NHEAD;
  float* wea = f + o;   o += 256;
  float* hpool = f + o; o += (size_t)NG * HC;
  float* ph = f + o;    o += (size_t)NG * 512;
  float* aep = f + o;   o += (size_t)3 * NE * 4;                     // [3][E][4] perm-ordered logits
  unsigned short* xb0 = (unsigned short*)(f + o);   o += (size_t)NN * DIN1 / 2;
  unsigned short* htb = (unsigned short*)(f + o);   o += (size_t)NN * HC / 2;
  unsigned short* xb = (unsigned short*)(f + o);    o += (size_t)NN * 384 / 2;
  unsigned short* wtb = (unsigned short*)(f + o);   o += (size_t)(128 * 64 + 2 * 128 * 128) / 2;
  unsigned short* lw1tb = (unsigned short*)(f + o); o += (512 * 384) / 2;
  int* row_start = (int*)(f + o);
  int* cnt = row_start + (NN + 1);
  int* fill = cnt + NN;
  int* aux = fill + NN;
  int* gs = aux + 256;
  int* srcp = gs + (NG + 1);

  const int NB = (NN + 255) / 256;
  const int EB = (NE + 255) / 256;

  hipMemsetAsync(cnt, 0, (size_t)2 * NN * sizeof(int), stream);  // cnt + fill

  k_we_a<<<1, 256, 0, stream>>>(We_[0], ae_[0], We_[1], ae_[1], We_[2], ae_[2], wea);
  k_lw1t<<<(512 * 384 + 255) / 256, 256, 0, stream>>>(lw1, lw1tb);
  k_wt<<<(128 * 64 + 2 * 128 * 128 + 255) / 256, 256, 0, stream>>>(W[0], W[1], W[2], wtb);
  k_cast<<<(NN * DIN1 + 255) / 256, 256, 0, stream>>>(x, xb0);
  k_hist<<<EB, 256, 0, stream>>>(dstp, cnt);
  k_scan1<<<NB, 256, 0, stream>>>(cnt, row_start, aux);
  k_scan2<<<1, 256, 0, stream>>>(aux, NB);
  k_scan3<<<NB, 256, 0, stream>>>(row_start, aux);
  k_scatter<<<EB, 256, 0, stream>>>(src, dstp, edge_attr, wea, row_start, fill, srcp, aep);
  k_gstart<<<NB, 256, 0, stream>>>(batch, gs);
  k_outinit<<<NB, 256, 0, stream>>>(out, lb2);

  const int CONVB = (NN + 127) / 128;
  unsigned short* wt_l[3] = {wtb, wtb + 128 * 64, wtb + 128 * 64 + 128 * 128};
  for (int l = 0; l < 3; ++l) {
    if (l == 0)
      k_conv_mfma<64, 64><<<CONVB, 256, 0, stream>>>(xb0, wt_l[0], htb);
    else if (l == 1)
      k_conv_mfma<128, 384><<<CONVB, 256, 0, stream>>>(xb, wt_l[1], htb);
    else
      k_conv_mfma<128, 384><<<CONVB, 256, 0, stream>>>(xb + 128, wt_l[2], htb);
    k_attn_node<<<(NN * NHEAD + 255) / 256, 256, 0, stream>>>(htb, as_[l], ad_[l], asrc, adst);
    k_aggregate<<<(NN + 3) / 4, 256, 0, stream>>>(htb, srcp, aep + (size_t)l * NE * 4, asrc, adst,
                                                  row_start, b_[l], xb, l * HC);
  }

  k_pool<<<NG, 128, 0, stream>>>(xb, gs, hpool);
  k_pool_gemm<<<dim3(4, NG / 16), 256, 0, stream>>>(hpool, lw1, ph);
  k_mlp_mfma<<<dim3(4, (NN + 127) / 128), 256, 0, stream>>>(xb, lw1tb, ph, batch, lb1, lw2, out);
}

// Round 4
// 597.673 us; speedup vs baseline: 2.6449x; 1.0229x over previous
//
#include <hip/hip_runtime.h>
#include <hip/hip_bf16.h>
#include <math.h>

#define NN 50000
#define NE 800000
#define DIN1 64
#define NHEAD 4
#define CH 32
#define HC 128
#define EDIM 16
#define NG 2000
#define SP 56     // LDS k-stride in bf16 elems
#define MAXCH 64  // edge chunk per node-wave

typedef __attribute__((ext_vector_type(8))) short short8;
typedef __attribute__((ext_vector_type(4))) float floatx4;

__device__ __forceinline__ float lrelu(float x, float s) { return x > 0.f ? x : s * x; }

__device__ __forceinline__ unsigned short f2bf(float x) {
  unsigned int u = __float_as_uint(x);
  u += 0x7fff + ((u >> 16) & 1);  // RNE
  return (unsigned short)(u >> 16);
}
__device__ __forceinline__ float bflo(unsigned int u) { return __uint_as_float(u << 16); }
__device__ __forceinline__ float bfhi(unsigned int u) { return __uint_as_float(u & 0xffff0000u); }

// ---------------- we_a precompute: we_a[l*64 + d*4 + h] = sum_c We_l[d, h*32+c]*ae_l[h,c]
__global__ __launch_bounds__(256) void k_we_a(
    const float* __restrict__ We1, const float* __restrict__ ae1,
    const float* __restrict__ We2, const float* __restrict__ ae2,
    const float* __restrict__ We3, const float* __restrict__ ae3,
    float* __restrict__ we_a) {
  int t = threadIdx.x;
  if (t >= 3 * EDIM * NHEAD) return;
  int l = t / (EDIM * NHEAD);
  int rem = t % (EDIM * NHEAD);
  int d = rem / NHEAD, h = rem % NHEAD;
  const float* We = (l == 0) ? We1 : ((l == 1) ? We2 : We3);
  const float* ae = (l == 0) ? ae1 : ((l == 1) ? ae2 : ae3);
  float s = 0.f;
  for (int c = 0; c < CH; ++c) s += We[d * HC + h * CH + c] * ae[h * CH + c];
  we_a[t] = s;
}

// ---------------- lw1 rows 0:384 -> transposed bf16 [512][384]
__global__ __launch_bounds__(256) void k_lw1t(const float* __restrict__ lw1, unsigned short* __restrict__ lw1tb) {
  int i = blockIdx.x * 256 + threadIdx.x;
  if (i >= 512 * 384) return;
  int n = i / 384, k = i % 384;
  lw1tb[i] = f2bf(lw1[(size_t)k * 512 + n]);
}

// ---------------- W1/W2/W3 -> transposed bf16: wt1[128][64], wt2[128][128], wt3[128][128]
__global__ __launch_bounds__(256) void k_wt(const float* __restrict__ W1, const float* __restrict__ W2,
                                            const float* __restrict__ W3, unsigned short* __restrict__ wtb) {
  int i = blockIdx.x * 256 + threadIdx.x;
  if (i < 128 * 64) {
    int j = i / 64, k = i % 64;
    wtb[i] = f2bf(W1[k * HC + j]);
  } else if (i < 128 * 64 + 128 * 128) {
    int ii = i - 128 * 64;
    int j = ii / 128, k = ii % 128;
    wtb[i] = f2bf(W2[k * HC + j]);
  } else if (i < 128 * 64 + 2 * 128 * 128) {
    int ii = i - (128 * 64 + 128 * 128);
    int j = ii / 128, k = ii % 128;
    wtb[i] = f2bf(W3[k * HC + j]);
  }
}

// ---------------- cast x fp32 -> bf16
__global__ __launch_bounds__(256) void k_cast(const float* __restrict__ x, unsigned short* __restrict__ xb0) {
  int i = blockIdx.x * 256 + threadIdx.x;
  if (i < NN * DIN1) xb0[i] = f2bf(x[i]);
}

// ---------------- CSR build
__global__ __launch_bounds__(256) void k_hist(const int* __restrict__ dst, int* __restrict__ cnt) {
  int e = blockIdx.x * 256 + threadIdx.x;
  if (e < NE) atomicAdd(&cnt[dst[e]], 1);
}

__global__ __launch_bounds__(256) void k_scan1(const int* __restrict__ cnt, int* __restrict__ row_start,
                                               int* __restrict__ aux) {
  __shared__ int s[256];
  int t = threadIdx.x;
  int i = blockIdx.x * 256 + t;
  int v = (i < NN) ? cnt[i] : 0;
  s[t] = v;
  __syncthreads();
  for (int off = 1; off < 256; off <<= 1) {
    int tv = (t >= off) ? s[t - off] : 0;
    __syncthreads();
    s[t] += tv;
    __syncthreads();
  }
  if (i < NN) row_start[i] = s[t] - v;
  if (t == 255) aux[blockIdx.x] = s[255];
}

__global__ __launch_bounds__(256) void k_scan2(int* __restrict__ aux, int nb) {
  __shared__ int s[256];
  int t = threadIdx.x;
  int v = (t < nb) ? aux[t] : 0;
  s[t] = v;
  __syncthreads();
  for (int off = 1; off < 256; off <<= 1) {
    int tv = (t >= off) ? s[t - off] : 0;
    __syncthreads();
    s[t] += tv;
    __syncthreads();
  }
  if (t < nb) aux[t] = s[t] - v;
}

__global__ __launch_bounds__(256) void k_scan3(int* __restrict__ row_start, const int* __restrict__ aux) {
  int i = blockIdx.x * 256 + threadIdx.x;
  if (i < NN) row_start[i] += aux[i >> 8];
  else if (i == NN) row_start[NN] = NE;
}

// ---------------- scatter: index only (4B writes, clustered per dst)
__global__ __launch_bounds__(256) void k_scatter(const int* __restrict__ dst, const int* __restrict__ row_start,
                                                 int* __restrict__ fill, int* __restrict__ perm) {
  int e = blockIdx.x * 256 + threadIdx.x;
  if (e >= NE) return;
  int d = dst[e];
  int p = atomicAdd(&fill[d], 1);
  perm[row_start[d] + p] = e;
}

// ---------------- permute: stream pos, gather e=perm[pos], write srcp + 3 aep planes coalesced
__global__ __launch_bounds__(256) void k_permute(const int* __restrict__ perm, const int* __restrict__ src,
                                                 const float* __restrict__ edge_attr, const float* __restrict__ wea,
                                                 int* __restrict__ srcp, float* __restrict__ aep) {
  __shared__ float wl[3 * EDIM * NHEAD];
  int t = threadIdx.x;
  if (t < 3 * EDIM * NHEAD) wl[t] = wea[t];
  __syncthreads();
  int pos = blockIdx.x * 256 + t;
  if (pos >= NE) return;
  int e = perm[pos];
  srcp[pos] = src[e];
  float ea[EDIM];
#pragma unroll
  for (int k = 0; k < EDIM; k += 4) {
    float4 v = *(const float4*)&edge_attr[(size_t)e * EDIM + k];
    ea[k] = v.x; ea[k + 1] = v.y; ea[k + 2] = v.z; ea[k + 3] = v.w;
  }
#pragma unroll
  for (int l = 0; l < 3; ++l) {
    float a0 = 0.f, a1 = 0.f, a2 = 0.f, a3 = 0.f;
#pragma unroll
    for (int k = 0; k < EDIM; ++k) {
      float ev = ea[k];
      a0 += ev * wl[l * 64 + k * 4 + 0];
      a1 += ev * wl[l * 64 + k * 4 + 1];
      a2 += ev * wl[l * 64 + k * 4 + 2];
      a3 += ev * wl[l * 64 + k * 4 + 3];
    }
    *(float4*)&aep[(size_t)l * NE * 4 + (size_t)pos * 4] = make_float4(a0, a1, a2, a3);
  }
}

// ---------------- graph ranges (batch is sorted)
__global__ __launch_bounds__(256) void k_gstart(const int* __restrict__ batch, int* __restrict__ gs) {
  int i = blockIdx.x * 256 + threadIdx.x;
  if (i >= NN) return;
  int b = batch[i];
  if (i == 0) {
    for (int g = 0; g <= b; ++g) gs[g] = 0;
  } else {
    int pb = batch[i - 1];
    for (int g = pb + 1; g <= b; ++g) gs[g] = i;
  }
  if (i == NN - 1) {
    for (int g = b + 1; g <= NG; ++g) gs[g] = NN;
  }
}

// ---------------- conv GEMM via MFMA with fused attention-dot epilogue:
// htb[n,:] = bf16(h); asrc[n,h]=sum_c h*a_s, adst[n,h]=sum_c h*a_d (fp32 acc)
template <int K, int ASTRIDE>
__global__ __launch_bounds__(256) void k_conv_mfma(const unsigned short* __restrict__ xin,
                                                   const unsigned short* __restrict__ wt,
                                                   const float* __restrict__ a_s, const float* __restrict__ a_d,
                                                   unsigned short* __restrict__ htb,
                                                   float* __restrict__ asrc, float* __restrict__ adst) {
  __shared__ unsigned short As[128 * SP];
  __shared__ unsigned short Bs[128 * SP];
  __shared__ float ss[HC], sd[HC];
  int t = threadIdx.x;
  int n0 = blockIdx.x * 128;
  int lane = t & 63;
  int wave = t >> 6;
  int wr = wave >> 1, wc = wave & 1;
  if (t < HC) ss[t] = a_s[t];
  else if (t < 2 * HC) sd[t - HC] = a_d[t - HC];

  floatx4 acc[4][4];
#pragma unroll
  for (int a = 0; a < 4; ++a)
#pragma unroll
    for (int b = 0; b < 4; ++b) acc[a][b] = (floatx4){0.f, 0.f, 0.f, 0.f};

  int sm = t & 127;
  int sc = (t >> 7) * 16;
  bool arow_ok = (n0 + sm) < NN;
  const unsigned short* aglob = xin + (size_t)(n0 + sm) * ASTRIDE + sc;
  const unsigned short* bglob = wt + sm * K + sc;
  unsigned short* asl = As + sm * SP + sc;
  unsigned short* bsl = Bs + sm * SP + sc;

  int frow = lane & 15, fk = (lane >> 4) * 8;
  const unsigned short* arow = As + (wr * 64 + frow) * SP + fk;
  const unsigned short* brow = Bs + (wc * 64 + frow) * SP + fk;

  for (int k0 = 0; k0 < K; k0 += 32) {
    uint4 a0 = arow_ok ? *(const uint4*)(aglob) : make_uint4(0, 0, 0, 0);
    uint4 a1 = arow_ok ? *(const uint4*)(aglob + 8) : make_uint4(0, 0, 0, 0);
    uint4 b0 = *(const uint4*)(bglob);
    uint4 b1 = *(const uint4*)(bglob + 8);
    aglob += 32;
    bglob += 32;
    __syncthreads();
    *(uint4*)(asl) = a0;
    *(uint4*)(asl + 8) = a1;
    *(uint4*)(bsl) = b0;
    *(uint4*)(bsl + 8) = b1;
    __syncthreads();
    short8 af[4], bf[4];
#pragma unroll
    for (int ti = 0; ti < 4; ++ti) af[ti] = *(const short8*)(arow + ti * 16 * SP);
#pragma unroll
    for (int tj = 0; tj < 4; ++tj) bf[tj] = *(const short8*)(brow + tj * 16 * SP);
#pragma unroll
    for (int ti = 0; ti < 4; ++ti)
#pragma unroll
      for (int tj = 0; tj < 4; ++tj)
        acc[ti][tj] = __builtin_amdgcn_mfma_f32_16x16x32_bf16(af[ti], bf[tj], acc[ti][tj], 0, 0, 0);
  }

  // epilogue: store htb + fused per-head dots. Wave (wr,wc) owns cols [wc*64, wc*64+64) = heads {wc*2, wc*2+1}
  int q = lane & 15;
  int colg = wc * 64 + q;
  int hb = wc * 2;
#pragma unroll
  for (int ti = 0; ti < 4; ++ti) {
    int rowb = n0 + wr * 64 + ti * 16 + (lane >> 4) * 4;
#pragma unroll
    for (int r = 0; r < 4; ++r) {
      int row = rowb + r;
      float v0 = acc[ti][0][r], v1 = acc[ti][1][r], v2 = acc[ti][2][r], v3 = acc[ti][3][r];
      if (row < NN) {
        htb[(size_t)row * HC + colg] = f2bf(v0);
        htb[(size_t)row * HC + colg + 16] = f2bf(v1);
        htb[(size_t)row * HC + colg + 32] = f2bf(v2);
        htb[(size_t)row * HC + colg + 48] = f2bf(v3);
      }
      float s0 = v0 * ss[colg] + v1 * ss[colg + 16];
      float s1 = v2 * ss[colg + 32] + v3 * ss[colg + 48];
      float dd0 = v0 * sd[colg] + v1 * sd[colg + 16];
      float dd1 = v2 * sd[colg + 32] + v3 * sd[colg + 48];
#pragma unroll
      for (int m = 1; m < 16; m <<= 1) {
        s0 += __shfl_xor(s0, m, 16);
        s1 += __shfl_xor(s1, m, 16);
        dd0 += __shfl_xor(dd0, m, 16);
        dd1 += __shfl_xor(dd1, m, 16);
      }
      if (q == 0 && row < NN) {
        asrc[row * 4 + hb] = s0;
        asrc[row * 4 + hb + 1] = s1;
        adst[row * 4 + hb] = dd0;
        adst[row * 4 + hb + 1] = dd1;
      }
    }
  }
}

// ---------------- fused alpha + softmax + aggregate. One wave per node.
__global__ __launch_bounds__(256) void k_aggregate(
    const unsigned short* __restrict__ htb, const int* __restrict__ srcp,
    const float* __restrict__ aep, const float* __restrict__ asrc, const float* __restrict__ adst,
    const int* __restrict__ row_start, const float* __restrict__ bias,
    unsigned short* __restrict__ xb, int col0) {
  __shared__ float exs[4][MAXCH][4];
  __shared__ int cns[4];
  int t = threadIdx.x;
  int lane = t & 63, wid = t >> 6;
  int n = blockIdx.x * 4 + wid;
  bool nok = n < NN;
  int rs = nok ? row_start[n] : 0;
  int re = nok ? row_start[n + 1] : 0;
  int deg = re - rs;
  if (lane == 0) cns[wid] = (deg + MAXCH - 1) / MAXCH;
  __syncthreads();
  int maxc = max(max(cns[0], cns[1]), max(cns[2], cns[3]));
  int q = lane & 15, g = lane >> 4;
  int h = q >> 2;
  float4 ad4 = nok ? *(const float4*)&adst[n * 4] : make_float4(0.f, 0.f, 0.f, 0.f);
  float acc[8];
#pragma unroll
  for (int j = 0; j < 8; ++j) acc[j] = 0.f;
  float d0 = 0.f, d1 = 0.f, d2 = 0.f, d3 = 0.f;

  for (int cc = 0; cc < maxc; ++cc) {
    int base = rs + cc * MAXCH;
    int m = re - base;
    if (m > MAXCH) m = MAXCH;
    if (lane < m) {
      int i = base + lane;
      int s = srcp[i];
      float4 ae = *(const float4*)&aep[(size_t)i * 4];
      float4 as4 = *(const float4*)&asrc[s * 4];
      float4 ex;
      ex.x = __expf(lrelu(as4.x + ad4.x + ae.x, 0.2f));
      ex.y = __expf(lrelu(as4.y + ad4.y + ae.y, 0.2f));
      ex.z = __expf(lrelu(as4.z + ad4.z + ae.z, 0.2f));
      ex.w = __expf(lrelu(as4.w + ad4.w + ae.w, 0.2f));
      *(float4*)&exs[wid][lane][0] = ex;
      d0 += ex.x; d1 += ex.y; d2 += ex.z; d3 += ex.w;
    }
    __syncthreads();
    int iters = (m > 0) ? ((m + 3) >> 2) : 0;
    for (int kk = 0; kk < iters; ++kk) {
      int ii = kk * 4 + g;
      if (ii < m) {
        int i = base + ii;
        int s = srcp[i];
        float w = exs[wid][ii][h];
        uint4 hv = *(const uint4*)(htb + (size_t)s * HC + q * 8);
        acc[0] += w * bflo(hv.x);
        acc[1] += w * bfhi(hv.x);
        acc[2] += w * bflo(hv.y);
        acc[3] += w * bfhi(hv.y);
        acc[4] += w * bflo(hv.z);
        acc[5] += w * bfhi(hv.z);
        acc[6] += w * bflo(hv.w);
        acc[7] += w * bfhi(hv.w);
      }
    }
    __syncthreads();
  }

#pragma unroll
  for (int mm = 1; mm < 64; mm <<= 1) {
    d0 += __shfl_xor(d0, mm, 64);
    d1 += __shfl_xor(d1, mm, 64);
    d2 += __shfl_xor(d2, mm, 64);
    d3 += __shfl_xor(d3, mm, 64);
  }
#pragma unroll
  for (int j = 0; j < 8; ++j) {
    acc[j] += __shfl_xor(acc[j], 16, 64);
    acc[j] += __shfl_xor(acc[j], 32, 64);
  }
  if (nok && g == 0) {
    float dh = (h == 0) ? d0 : ((h == 1) ? d1 : ((h == 2) ? d2 : d3));
    float inv = 1.f / (dh + 1e-16f);
    unsigned int w[4];
#pragma unroll
    for (int j = 0; j < 4; ++j) {
      float v0 = acc[2 * j] * inv + bias[q * 8 + 2 * j];
      float v1 = acc[2 * j + 1] * inv + bias[q * 8 + 2 * j + 1];
      w[j] = (unsigned int)f2bf(v0) | ((unsigned int)f2bf(v1) << 16);
    }
    *(uint4*)&xb[(size_t)n * 384 + col0 + q * 8] = make_uint4(w[0], w[1], w[2], w[3]);
  }
}

// ---------------- global add pool from xb col slice 256:384 (= h3)
__global__ __launch_bounds__(128) void k_pool(const unsigned short* __restrict__ xb, const int* __restrict__ gs,
                                              float* __restrict__ hpool) {
  int g = blockIdx.x;
  int j = threadIdx.x;
  int s = gs[g], e = gs[g + 1];
  float acc = 0.f;
  for (int i = s; i < e; ++i) acc += bflo((unsigned int)xb[(size_t)i * 384 + 256 + j]);
  hpool[(size_t)g * HC + j] = acc;
}

// ---------------- ph[g,0:512] = hpool[g,0:128] @ lw1[384:512, 0:512]
__global__ __launch_bounds__(256) void k_pool_gemm(const float* __restrict__ hpool, const float* __restrict__ lw1,
                                                   float* __restrict__ ph) {
  __shared__ float hp[16][128];
  int t = threadIdx.x;
  int j0 = blockIdx.x * 128;
  int g0 = blockIdx.y * 16;
  int jj = t & 127, gg = t >> 7;
#pragma unroll
  for (int i = 0; i < 8; ++i) {
    int q = t + 256 * i;
    int row = q >> 7, col = q & 127;
    hp[row][col] = hpool[(size_t)(g0 + row) * HC + col];
  }
  __syncthreads();
  float acc[8];
#pragma unroll
  for (int i = 0; i < 8; ++i) acc[i] = 0.f;
  for (int k = 0; k < HC; ++k) {
    float wv = lw1[(size_t)(384 + k) * 512 + j0 + jj];
#pragma unroll
    for (int gi = 0; gi < 8; ++gi) acc[gi] += hp[gg + 2 * gi][k] * wv;
  }
#pragma unroll
  for (int gi = 0; gi < 8; ++gi) ph[(size_t)(g0 + gg + 2 * gi) * 512 + j0 + jj] = acc[gi];
}

__global__ __launch_bounds__(256) void k_outinit(float* __restrict__ out, const float* __restrict__ lb2) {
  int i = blockIdx.x * 256 + threadIdx.x;
  if (i < NN) out[i] = lb2[0];
}

// ---------------- fused MLP via bf16 MFMA
__global__ __launch_bounds__(256) void k_mlp_mfma(
    const unsigned short* __restrict__ xb, const unsigned short* __restrict__ lw1tb,
    const float* __restrict__ ph, const int* __restrict__ batch,
    const float* __restrict__ lb1, const float* __restrict__ lw2,
    float* __restrict__ out) {
  __shared__ unsigned short As[128 * SP];
  __shared__ unsigned short Bs[128 * SP];
  int t = threadIdx.x;
  int j0 = blockIdx.x * 128;
  int n0 = blockIdx.y * 128;
  int lane = t & 63;
  int wave = t >> 6;
  int wr = wave >> 1, wc = wave & 1;

  floatx4 acc[4][4];
#pragma unroll
  for (int a = 0; a < 4; ++a)
#pragma unroll
    for (int b = 0; b < 4; ++b) acc[a][b] = (floatx4){0.f, 0.f, 0.f, 0.f};

  int sm = t & 127;
  int sc = (t >> 7) * 16;
  bool arow_ok = (n0 + sm) < NN;
  const unsigned short* aglob = xb + (size_t)(n0 + sm) * 384 + sc;
  const unsigned short* bglob = lw1tb + (size_t)(j0 + sm) * 384 + sc;
  unsigned short* asl = As + sm * SP + sc;
  unsigned short* bsl = Bs + sm * SP + sc;

  int frow = lane & 15, fk = (lane >> 4) * 8;
  const unsigned short* arow = As + (wr * 64 + frow) * SP + fk;
  const unsigned short* brow = Bs + (wc * 64 + frow) * SP + fk;

  for (int k0 = 0; k0 < 384; k0 += 32) {
    uint4 a0 = arow_ok ? *(const uint4*)(aglob) : make_uint4(0, 0, 0, 0);
    uint4 a1 = arow_ok ? *(const uint4*)(aglob + 8) : make_uint4(0, 0, 0, 0);
    uint4 b0 = *(const uint4*)(bglob);
    uint4 b1 = *(const uint4*)(bglob + 8);
    aglob += 32;
    bglob += 32;
    __syncthreads();
    *(uint4*)(asl) = a0;
    *(uint4*)(asl + 8) = a1;
    *(uint4*)(bsl) = b0;
    *(uint4*)(bsl + 8) = b1;
    __syncthreads();
    short8 af[4], bf[4];
#pragma unroll
    for (int ti = 0; ti < 4; ++ti) af[ti] = *(const short8*)(arow + ti * 16 * SP);
#pragma unroll
    for (int tj = 0; tj < 4; ++tj) bf[tj] = *(const short8*)(brow + tj * 16 * SP);
#pragma unroll
    for (int ti = 0; ti < 4; ++ti)
#pragma unroll
      for (int tj = 0; tj < 4; ++tj)
        acc[ti][tj] = __builtin_amdgcn_mfma_f32_16x16x32_bf16(af[ti], bf[tj], acc[ti][tj], 0, 0, 0);
  }

  int colg = j0 + wc * 64 + (lane & 15);
#pragma unroll
  for (int ti = 0; ti < 4; ++ti) {
    int rowb = n0 + wr * 64 + ti * 16 + (lane >> 4) * 4;
#pragma unroll
    for (int r = 0; r < 4; ++r) {
      int row = rowb + r;
      int rc = (row < NN) ? row : 0;
      int bg = batch[rc];
      float partial = 0.f;
#pragma unroll
      for (int tj = 0; tj < 4; ++tj) {
        int j = colg + tj * 16;
        float v = acc[ti][tj][r] + ph[(size_t)bg * 512 + j] + lb1[j];
        partial += lrelu(v, 0.01f) * lw2[j];
      }
#pragma unroll
      for (int m = 1; m < 16; m <<= 1) partial += __shfl_xor(partial, m, 16);
      if ((lane & 15) == 0 && row < NN) atomicAdd(&out[row], partial);
    }
  }
}

extern "C" void kernel_launch(void* const* d_in, const int* in_sizes, int n_in,
                              void* d_out, int out_size, void* d_ws, size_t ws_size,
                              hipStream_t stream) {
  const float* x = (const float*)d_in[0];
  const int* edge_index = (const int*)d_in[1];
  const int* src = edge_index;
  const int* dstp = edge_index + NE;
  const float* edge_attr = (const float*)d_in[2];
  const int* batch = (const int*)d_in[3];
  const float* W[3] = {(const float*)d_in[4], (const float*)d_in[10], (const float*)d_in[16]};
  const float* as_[3] = {(const float*)d_in[5], (const float*)d_in[11], (const float*)d_in[17]};
  const float* ad_[3] = {(const float*)d_in[6], (const float*)d_in[12], (const float*)d_in[18]};
  const float* We_[3] = {(const float*)d_in[7], (const float*)d_in[13], (const float*)d_in[19]};
  const float* ae_[3] = {(const float*)d_in[8], (const float*)d_in[14], (const float*)d_in[20]};
  const float* b_[3] = {(const float*)d_in[9], (const float*)d_in[15], (const float*)d_in[21]};
  const float* lw1 = (const float*)d_in[22];
  const float* lb1 = (const float*)d_in[23];
  const float* lw2 = (const float*)d_in[24];
  const float* lb2 = (const float*)d_in[25];
  float* out = (float*)d_out;

  // workspace carve-up
  float* f = (float*)d_ws;
  size_t o = 0;  // in floats
  float* asrc = f + o;  o += (size_t)NN * NHEAD;
  float* adst = f + o;  o += (size_t)NN * NHEAD;
  float* wea = f + o;   o += 256;
  float* hpool = f + o; o += (size_t)NG * HC;
  float* ph = f + o;    o += (size_t)NG * 512;
  float* aep = f + o;   o += (size_t)3 * NE * 4;                     // [3][E][4] perm-ordered logits
  unsigned short* xb0 = (unsigned short*)(f + o);   o += (size_t)NN * DIN1 / 2;
  unsigned short* htb = (unsigned short*)(f + o);   o += (size_t)NN * HC / 2;
  unsigned short* xb = (unsigned short*)(f + o);    o += (size_t)NN * 384 / 2;
  unsigned short* wtb = (unsigned short*)(f + o);   o += (size_t)(128 * 64 + 2 * 128 * 128) / 2;
  unsigned short* lw1tb = (unsigned short*)(f + o); o += (512 * 384) / 2;
  int* row_start = (int*)(f + o);
  int* cnt = row_start + (NN + 1);
  int* fill = cnt + NN;
  int* aux = fill + NN;
  int* gs = aux + 256;
  int* perm = gs + (NG + 1);
  int* srcp = perm + NE;

  const int NB = (NN + 255) / 256;
  const int EB = (NE + 255) / 256;

  hipMemsetAsync(cnt, 0, (size_t)2 * NN * sizeof(int), stream);  // cnt + fill

  k_we_a<<<1, 256, 0, stream>>>(We_[0], ae_[0], We_[1], ae_[1], We_[2], ae_[2], wea);
  k_lw1t<<<(512 * 384 + 255) / 256, 256, 0, stream>>>(lw1, lw1tb);
  k_wt<<<(128 * 64 + 2 * 128 * 128 + 255) / 256, 256, 0, stream>>>(W[0], W[1], W[2], wtb);
  k_cast<<<(NN * DIN1 + 255) / 256, 256, 0, stream>>>(x, xb0);
  k_hist<<<EB, 256, 0, stream>>>(dstp, cnt);
  k_scan1<<<NB, 256, 0, stream>>>(cnt, row_start, aux);
  k_scan2<<<1, 256, 0, stream>>>(aux, NB);
  k_scan3<<<NB, 256, 0, stream>>>(row_start, aux);
  k_scatter<<<EB, 256, 0, stream>>>(dstp, row_start, fill, perm);
  k_permute<<<EB, 256, 0, stream>>>(perm, src, edge_attr, wea, srcp, aep);
  k_gstart<<<NB, 256, 0, stream>>>(batch, gs);
  k_outinit<<<NB, 256, 0, stream>>>(out, lb2);

  const int CONVB = (NN + 127) / 128;
  unsigned short* wt_l[3] = {wtb, wtb + 128 * 64, wtb + 128 * 64 + 128 * 128};
  for (int l = 0; l < 3; ++l) {
    if (l == 0)
      k_conv_mfma<64, 64><<<CONVB, 256, 0, stream>>>(xb0, wt_l[0], as_[0], ad_[0], htb, asrc, adst);
    else if (l == 1)
      k_conv_mfma<128, 384><<<CONVB, 256, 0, stream>>>(xb, wt_l[1], as_[1], ad_[1], htb, asrc, adst);
    else
      k_conv_mfma<128, 384><<<CONVB, 256, 0, stream>>>(xb + 128, wt_l[2], as_[2], ad_[2], htb, asrc, adst);
    k_aggregate<<<(NN + 3) / 4, 256, 0, stream>>>(htb, srcp, aep + (size_t)l * NE * 4, asrc, adst,
                                                  row_start, b_[l], xb, l * HC);
  }

  k_pool<<<NG, 128, 0, stream>>>(xb, gs, hpool);
  k_pool_gemm<<<dim3(4, NG / 16), 256, 0, stream>>>(hpool, lw1, ph);
  k_mlp_mfma<<<dim3(4, (NN + 127) / 128), 256, 0, stream>>>(xb, lw1tb, ph, batch, lb1, lw2, out);
}

// Round 5
// 559.836 us; speedup vs baseline: 2.8237x; 1.0676x over previous
//
#include <hip/hip_runtime.h>
#include <hip/hip_bf16.h>
#include <math.h>

#define NN 50000
#define NE 800000
#define DIN1 64
#define NHEAD 4
#define CH 32
#define HC 128
#define EDIM 16
#define NG 2000
#define SP 56     // LDS k-stride in bf16 elems (conv kernels)
#define MAXCH 64  // edge chunk per node-wave
#define MJ 256    // mlp cols per block

typedef __attribute__((ext_vector_type(8))) short short8;
typedef __attribute__((ext_vector_type(4))) float floatx4;

__device__ __forceinline__ float lrelu(float x, float s) { return x > 0.f ? x : s * x; }

__device__ __forceinline__ unsigned short f2bf(float x) {
  unsigned int u = __float_as_uint(x);
  u += 0x7fff + ((u >> 16) & 1);  // RNE
  return (unsigned short)(u >> 16);
}
__device__ __forceinline__ float bflo(unsigned int u) { return __uint_as_float(u << 16); }
__device__ __forceinline__ float bfhi(unsigned int u) { return __uint_as_float(u & 0xffff0000u); }

// async global->LDS, 16B per lane; lds must be wave-uniform, lanes land at lds + lane*16
__device__ __forceinline__ void async16(void* lds, const void* g) {
  __builtin_amdgcn_global_load_lds((const __attribute__((address_space(1))) unsigned int*)g,
                                   (__attribute__((address_space(3))) unsigned int*)lds, 16, 0, 0);
}

// ---------------- we_a precompute: we_a[l*64 + d*4 + h] = sum_c We_l[d, h*32+c]*ae_l[h,c]
__global__ __launch_bounds__(256) void k_we_a(
    const float* __restrict__ We1, const float* __restrict__ ae1,
    const float* __restrict__ We2, const float* __restrict__ ae2,
    const float* __restrict__ We3, const float* __restrict__ ae3,
    float* __restrict__ we_a) {
  int t = threadIdx.x;
  if (t >= 3 * EDIM * NHEAD) return;
  int l = t / (EDIM * NHEAD);
  int rem = t % (EDIM * NHEAD);
  int d = rem / NHEAD, h = rem % NHEAD;
  const float* We = (l == 0) ? We1 : ((l == 1) ? We2 : We3);
  const float* ae = (l == 0) ? ae1 : ((l == 1) ? ae2 : ae3);
  float s = 0.f;
  for (int c = 0; c < CH; ++c) s += We[d * HC + h * CH + c] * ae[h * CH + c];
  we_a[t] = s;
}

// ---------------- wsd[l][col][k] bf16 (stride 128): col<4: (W a_s)|head col ; col in 4..7: (W a_d); 8..15: 0
__global__ __launch_bounds__(256) void k_wsd(
    const float* __restrict__ W1, const float* __restrict__ as1, const float* __restrict__ ad1,
    const float* __restrict__ W2, const float* __restrict__ as2, const float* __restrict__ ad2,
    const float* __restrict__ W3, const float* __restrict__ as3, const float* __restrict__ ad3,
    unsigned short* __restrict__ wsdb) {
  int i = blockIdx.x * 256 + threadIdx.x;
  if (i >= 3 * 16 * 128) return;
  int l = i >> 11;
  int col = (i >> 7) & 15;
  int k = i & 127;
  if (col >= 8 || (l == 0 && k >= DIN1)) { wsdb[i] = 0; return; }
  const float* W = (l == 0) ? W1 : ((l == 1) ? W2 : W3);
  int head = col & 3;
  const float* av = (col < 4) ? ((l == 0) ? as1 : ((l == 1) ? as2 : as3))
                              : ((l == 0) ? ad1 : ((l == 1) ? ad2 : ad3));
  float s = 0.f;
  for (int c = 0; c < CH; ++c) s += W[(size_t)k * HC + head * CH + c] * av[head * CH + c];
  wsdb[i] = f2bf(s);
}

// ---------------- lw1 rows 0:384 -> transposed bf16 [512][384]
__global__ __launch_bounds__(256) void k_lw1t(const float* __restrict__ lw1, unsigned short* __restrict__ lw1tb) {
  int i = blockIdx.x * 256 + threadIdx.x;
  if (i >= 512 * 384) return;
  int n = i / 384, k = i % 384;
  lw1tb[i] = f2bf(lw1[(size_t)k * 512 + n]);
}

// ---------------- W1/W2/W3 -> transposed bf16: wt1[128][64], wt2[128][128], wt3[128][128]
__global__ __launch_bounds__(256) void k_wt(const float* __restrict__ W1, const float* __restrict__ W2,
                                            const float* __restrict__ W3, unsigned short* __restrict__ wtb) {
  int i = blockIdx.x * 256 + threadIdx.x;
  if (i < 128 * 64) {
    int j = i / 64, k = i % 64;
    wtb[i] = f2bf(W1[k * HC + j]);
  } else if (i < 128 * 64 + 128 * 128) {
    int ii = i - 128 * 64;
    int j = ii / 128, k = ii % 128;
    wtb[i] = f2bf(W2[k * HC + j]);
  } else if (i < 128 * 64 + 2 * 128 * 128) {
    int ii = i - (128 * 64 + 128 * 128);
    int j = ii / 128, k = ii % 128;
    wtb[i] = f2bf(W3[k * HC + j]);
  }
}

// ---------------- cast x fp32 -> bf16
__global__ __launch_bounds__(256) void k_cast(const float* __restrict__ x, unsigned short* __restrict__ xb0) {
  int i = blockIdx.x * 256 + threadIdx.x;
  if (i < NN * DIN1) xb0[i] = f2bf(x[i]);
}

// ---------------- CSR build
__global__ __launch_bounds__(256) void k_hist(const int* __restrict__ dst, int* __restrict__ cnt) {
  int e = blockIdx.x * 256 + threadIdx.x;
  if (e < NE) atomicAdd(&cnt[dst[e]], 1);
}

__global__ __launch_bounds__(256) void k_scan1(const int* __restrict__ cnt, int* __restrict__ row_start,
                                               int* __restrict__ aux) {
  __shared__ int s[256];
  int t = threadIdx.x;
  int i = blockIdx.x * 256 + t;
  int v = (i < NN) ? cnt[i] : 0;
  s[t] = v;
  __syncthreads();
  for (int off = 1; off < 256; off <<= 1) {
    int tv = (t >= off) ? s[t - off] : 0;
    __syncthreads();
    s[t] += tv;
    __syncthreads();
  }
  if (i < NN) row_start[i] = s[t] - v;
  if (t == 255) aux[blockIdx.x] = s[255];
}

__global__ __launch_bounds__(256) void k_scan2(int* __restrict__ aux, int nb) {
  __shared__ int s[256];
  int t = threadIdx.x;
  int v = (t < nb) ? aux[t] : 0;
  s[t] = v;
  __syncthreads();
  for (int off = 1; off < 256; off <<= 1) {
    int tv = (t >= off) ? s[t - off] : 0;
    __syncthreads();
    s[t] += tv;
    __syncthreads();
  }
  if (t < nb) aux[t] = s[t] - v;
}

__global__ __launch_bounds__(256) void k_scan3(int* __restrict__ row_start, const int* __restrict__ aux) {
  int i = blockIdx.x * 256 + threadIdx.x;
  if (i < NN) row_start[i] += aux[i >> 8];
  else if (i == NN) row_start[NN] = NE;
}

// ---------------- scatter: index only (4B writes, clustered per dst)
__global__ __launch_bounds__(256) void k_scatter(const int* __restrict__ dst, const int* __restrict__ row_start,
                                                 int* __restrict__ fill, int* __restrict__ perm) {
  int e = blockIdx.x * 256 + threadIdx.x;
  if (e >= NE) return;
  int d = dst[e];
  int p = atomicAdd(&fill[d], 1);
  perm[row_start[d] + p] = e;
}

// ---------------- permute: stream pos, gather e=perm[pos], write srcp + 3 aep planes coalesced
__global__ __launch_bounds__(256) void k_permute(const int* __restrict__ perm, const int* __restrict__ src,
                                                 const float* __restrict__ edge_attr, const float* __restrict__ wea,
                                                 int* __restrict__ srcp, float* __restrict__ aep) {
  __shared__ float wl[3 * EDIM * NHEAD];
  int t = threadIdx.x;
  if (t < 3 * EDIM * NHEAD) wl[t] = wea[t];
  __syncthreads();
  int pos = blockIdx.x * 256 + t;
  if (pos >= NE) return;
  int e = perm[pos];
  srcp[pos] = src[e];
  float ea[EDIM];
#pragma unroll
  for (int k = 0; k < EDIM; k += 4) {
    float4 v = *(const float4*)&edge_attr[(size_t)e * EDIM + k];
    ea[k] = v.x; ea[k + 1] = v.y; ea[k + 2] = v.z; ea[k + 3] = v.w;
  }
#pragma unroll
  for (int l = 0; l < 3; ++l) {
    float a0 = 0.f, a1 = 0.f, a2 = 0.f, a3 = 0.f;
#pragma unroll
    for (int k = 0; k < EDIM; ++k) {
      float ev = ea[k];
      a0 += ev * wl[l * 64 + k * 4 + 0];
      a1 += ev * wl[l * 64 + k * 4 + 1];
      a2 += ev * wl[l * 64 + k * 4 + 2];
      a3 += ev * wl[l * 64 + k * 4 + 3];
    }
    *(float4*)&aep[(size_t)l * NE * 4 + (size_t)pos * 4] = make_float4(a0, a1, a2, a3);
  }
}

// ---------------- graph ranges (batch is sorted)
__global__ __launch_bounds__(256) void k_gstart(const int* __restrict__ batch, int* __restrict__ gs) {
  int i = blockIdx.x * 256 + threadIdx.x;
  if (i >= NN) return;
  int b = batch[i];
  if (i == 0) {
    for (int g = 0; g <= b; ++g) gs[g] = 0;
  } else {
    int pb = batch[i - 1];
    for (int g = pb + 1; g <= b; ++g) gs[g] = i;
  }
  if (i == NN - 1) {
    for (int g = b + 1; g <= NG; ++g) gs[g] = NN;
  }
}

// ---------------- conv GEMM via MFMA; attention dots as an extra MFMA tile (cols = wsd)
template <int K, int ASTRIDE>
__global__ __launch_bounds__(256) void k_conv_mfma(const unsigned short* __restrict__ xin,
                                                   const unsigned short* __restrict__ wt,
                                                   const unsigned short* __restrict__ wsd,
                                                   unsigned short* __restrict__ htb,
                                                   float* __restrict__ asrc, float* __restrict__ adst) {
  __shared__ unsigned short As[128 * SP];
  __shared__ unsigned short Bs[128 * SP];
  __shared__ unsigned short Bs2[16 * SP];
  int t = threadIdx.x;
  int n0 = blockIdx.x * 128;
  int lane = t & 63;
  int wave = t >> 6;
  int wr = wave >> 1, wc = wave & 1;

  floatx4 acc[4][4];
  floatx4 acce[4];
#pragma unroll
  for (int a = 0; a < 4; ++a) {
    acce[a] = (floatx4){0.f, 0.f, 0.f, 0.f};
#pragma unroll
    for (int b = 0; b < 4; ++b) acc[a][b] = (floatx4){0.f, 0.f, 0.f, 0.f};
  }

  int sm = t & 127;
  int sc = (t >> 7) * 16;
  int arow = n0 + sm;
  if (arow >= NN) arow = NN - 1;  // clamp; results for OOB rows discarded
  const unsigned short* aglob = xin + (size_t)arow * ASTRIDE + sc;
  const unsigned short* bglob = wt + sm * K + sc;
  unsigned short* asl = As + sm * SP + sc;
  unsigned short* bsl = Bs + sm * SP + sc;

  int frow = lane & 15, fk = (lane >> 4) * 8;
  const unsigned short* arow_p = As + (wr * 64 + frow) * SP + fk;
  const unsigned short* brow_p = Bs + (wc * 64 + frow) * SP + fk;
  const unsigned short* b2row_p = Bs2 + frow * SP + fk;

  for (int k0 = 0; k0 < K; k0 += 32) {
    uint4 a0 = *(const uint4*)(aglob);
    uint4 a1 = *(const uint4*)(aglob + 8);
    uint4 b0 = *(const uint4*)(bglob);
    uint4 b1 = *(const uint4*)(bglob + 8);
    uint4 b2 = make_uint4(0, 0, 0, 0);
    if (t < 64) b2 = *(const uint4*)(wsd + (t >> 2) * 128 + k0 + (t & 3) * 8);
    aglob += 32;
    bglob += 32;
    __syncthreads();
    *(uint4*)(asl) = a0;
    *(uint4*)(asl + 8) = a1;
    *(uint4*)(bsl) = b0;
    *(uint4*)(bsl + 8) = b1;
    if (t < 64) *(uint4*)(Bs2 + (t >> 2) * SP + (t & 3) * 8) = b2;
    __syncthreads();
    short8 af[4], bf[4];
#pragma unroll
    for (int ti = 0; ti < 4; ++ti) af[ti] = *(const short8*)(arow_p + ti * 16 * SP);
#pragma unroll
    for (int tj = 0; tj < 4; ++tj) bf[tj] = *(const short8*)(brow_p + tj * 16 * SP);
#pragma unroll
    for (int ti = 0; ti < 4; ++ti)
#pragma unroll
      for (int tj = 0; tj < 4; ++tj)
        acc[ti][tj] = __builtin_amdgcn_mfma_f32_16x16x32_bf16(af[ti], bf[tj], acc[ti][tj], 0, 0, 0);
    if (wc == 0) {
      short8 bf2 = *(const short8*)(b2row_p);
#pragma unroll
      for (int ti = 0; ti < 4; ++ti)
        acce[ti] = __builtin_amdgcn_mfma_f32_16x16x32_bf16(af[ti], bf2, acce[ti], 0, 0, 0);
    }
    arow_p += 0;  // keep pointers (LDS reused each iter)
  }

  int q = lane & 15;
  int colg = wc * 64 + q;
#pragma unroll
  for (int ti = 0; ti < 4; ++ti) {
    int rowb = n0 + wr * 64 + ti * 16 + (lane >> 4) * 4;
#pragma unroll
    for (int r = 0; r < 4; ++r) {
      int row = rowb + r;
      if (row < NN) {
        htb[(size_t)row * HC + colg] = f2bf(acc[ti][0][r]);
        htb[(size_t)row * HC + colg + 16] = f2bf(acc[ti][1][r]);
        htb[(size_t)row * HC + colg + 32] = f2bf(acc[ti][2][r]);
        htb[(size_t)row * HC + colg + 48] = f2bf(acc[ti][3][r]);
        if (wc == 0 && q < 8) {
          float v = acce[ti][r];
          if (q < 4) asrc[row * 4 + q] = v;
          else adst[row * 4 + (q - 4)] = v;
        }
      }
    }
  }
}

// ---------------- fused alpha + softmax + aggregate. One wave per node. 2x-unrolled gather.
__global__ __launch_bounds__(256) void k_aggregate(
    const unsigned short* __restrict__ htb, const int* __restrict__ srcp,
    const float* __restrict__ aep, const float* __restrict__ asrc, const float* __restrict__ adst,
    const int* __restrict__ row_start, const float* __restrict__ bias,
    unsigned short* __restrict__ xb, int col0) {
  __shared__ float exs[4][MAXCH][4];
  __shared__ int cns[4];
  int t = threadIdx.x;
  int lane = t & 63, wid = t >> 6;
  int n = blockIdx.x * 4 + wid;
  bool nok = n < NN;
  int rs = nok ? row_start[n] : 0;
  int re = nok ? row_start[n + 1] : 0;
  int deg = re - rs;
  if (lane == 0) cns[wid] = (deg + MAXCH - 1) / MAXCH;
  __syncthreads();
  int maxc = max(max(cns[0], cns[1]), max(cns[2], cns[3]));
  int q = lane & 15, g = lane >> 4;
  int h = q >> 2;
  float4 ad4 = nok ? *(const float4*)&adst[n * 4] : make_float4(0.f, 0.f, 0.f, 0.f);
  float acc[8];
#pragma unroll
  for (int j = 0; j < 8; ++j) acc[j] = 0.f;
  float d0 = 0.f, d1 = 0.f, d2 = 0.f, d3 = 0.f;

  for (int cc = 0; cc < maxc; ++cc) {
    int base = rs + cc * MAXCH;
    int m = re - base;
    if (m > MAXCH) m = MAXCH;
    if (lane < m) {
      int i = base + lane;
      int s = srcp[i];
      float4 ae = *(const float4*)&aep[(size_t)i * 4];
      float4 as4 = *(const float4*)&asrc[s * 4];
      float4 ex;
      ex.x = __expf(lrelu(as4.x + ad4.x + ae.x, 0.2f));
      ex.y = __expf(lrelu(as4.y + ad4.y + ae.y, 0.2f));
      ex.z = __expf(lrelu(as4.z + ad4.z + ae.z, 0.2f));
      ex.w = __expf(lrelu(as4.w + ad4.w + ae.w, 0.2f));
      *(float4*)&exs[wid][lane][0] = ex;
      d0 += ex.x; d1 += ex.y; d2 += ex.z; d3 += ex.w;
    }
    __syncthreads();
    int iters = (m > 0) ? ((m + 7) >> 3) : 0;
    for (int kk = 0; kk < iters; ++kk) {
      int ii0 = kk * 8 + g;
      int ii1 = ii0 + 4;
      int i0 = base + ((ii0 < m) ? ii0 : 0);
      int i1 = base + ((ii1 < m) ? ii1 : 0);
      int s0 = srcp[i0];
      int s1 = srcp[i1];
      uint4 h0 = *(const uint4*)(htb + (size_t)s0 * HC + q * 8);
      uint4 h1 = *(const uint4*)(htb + (size_t)s1 * HC + q * 8);
      float w0 = (ii0 < m) ? exs[wid][ii0][h] : 0.f;
      float w1 = (ii1 < m) ? exs[wid][ii1][h] : 0.f;
      acc[0] += w0 * bflo(h0.x) + w1 * bflo(h1.x);
      acc[1] += w0 * bfhi(h0.x) + w1 * bfhi(h1.x);
      acc[2] += w0 * bflo(h0.y) + w1 * bflo(h1.y);
      acc[3] += w0 * bfhi(h0.y) + w1 * bfhi(h1.y);
      acc[4] += w0 * bflo(h0.z) + w1 * bflo(h1.z);
      acc[5] += w0 * bfhi(h0.z) + w1 * bfhi(h1.z);
      acc[6] += w0 * bflo(h0.w) + w1 * bflo(h1.w);
      acc[7] += w0 * bfhi(h0.w) + w1 * bfhi(h1.w);
    }
    __syncthreads();
  }

#pragma unroll
  for (int mm = 1; mm < 64; mm <<= 1) {
    d0 += __shfl_xor(d0, mm, 64);
    d1 += __shfl_xor(d1, mm, 64);
    d2 += __shfl_xor(d2, mm, 64);
    d3 += __shfl_xor(d3, mm, 64);
  }
#pragma unroll
  for (int j = 0; j < 8; ++j) {
    acc[j] += __shfl_xor(acc[j], 16, 64);
    acc[j] += __shfl_xor(acc[j], 32, 64);
  }
  if (nok && g == 0) {
    float dh = (h == 0) ? d0 : ((h == 1) ? d1 : ((h == 2) ? d2 : d3));
    float inv = 1.f / (dh + 1e-16f);
    unsigned int w[4];
#pragma unroll
    for (int j = 0; j < 4; ++j) {
      float v0 = acc[2 * j] * inv + bias[q * 8 + 2 * j];
      float v1 = acc[2 * j + 1] * inv + bias[q * 8 + 2 * j + 1];
      w[j] = (unsigned int)f2bf(v0) | ((unsigned int)f2bf(v1) << 16);
    }
    *(uint4*)&xb[(size_t)n * 384 + col0 + q * 8] = make_uint4(w[0], w[1], w[2], w[3]);
  }
}

// ---------------- global add pool from xb col slice 256:384 (= h3)
__global__ __launch_bounds__(128) void k_pool(const unsigned short* __restrict__ xb, const int* __restrict__ gs,
                                              float* __restrict__ hpool) {
  int g = blockIdx.x;
  int j = threadIdx.x;
  int s = gs[g], e = gs[g + 1];
  float acc = 0.f;
  for (int i = s; i < e; ++i) acc += bflo((unsigned int)xb[(size_t)i * 384 + 256 + j]);
  hpool[(size_t)g * HC + j] = acc;
}

// ---------------- ph[g,0:512] = hpool[g,0:128] @ lw1[384:512, 0:512]
__global__ __launch_bounds__(256) void k_pool_gemm(const float* __restrict__ hpool, const float* __restrict__ lw1,
                                                   float* __restrict__ ph) {
  __shared__ float hp[16][128];
  int t = threadIdx.x;
  int j0 = blockIdx.x * 128;
  int g0 = blockIdx.y * 16;
  int jj = t & 127, gg = t >> 7;
#pragma unroll
  for (int i = 0; i < 8; ++i) {
    int q = t + 256 * i;
    int row = q >> 7, col = q & 127;
    hp[row][col] = hpool[(size_t)(g0 + row) * HC + col];
  }
  __syncthreads();
  float acc[8];
#pragma unroll
  for (int i = 0; i < 8; ++i) acc[i] = 0.f;
  for (int k = 0; k < HC; ++k) {
    float wv = lw1[(size_t)(384 + k) * 512 + j0 + jj];
#pragma unroll
    for (int gi = 0; gi < 8; ++gi) acc[gi] += hp[gg + 2 * gi][k] * wv;
  }
#pragma unroll
  for (int gi = 0; gi < 8; ++gi) ph[(size_t)(g0 + gg + 2 * gi) * 512 + j0 + jj] = acc[gi];
}

__global__ __launch_bounds__(256) void k_outinit(float* __restrict__ out, const float* __restrict__ lb2) {
  int i = blockIdx.x * 256 + threadIdx.x;
  if (i < NN) out[i] = lb2[0];
}

// ---------------- fused MLP via bf16 MFMA, async global_load_lds staging.
// Tile 128 rows x 256 cols; 4 waves in 2x2 (64 rows x 128 cols each); acc 4x8.
// LDS layout: chunk-linear [kc][row] (A) / [kc][col] (B), 16B chunks, tid-contiguous.
__global__ __launch_bounds__(256, 2) void k_mlp_mfma(
    const unsigned short* __restrict__ xb, const unsigned short* __restrict__ lw1tb,
    const float* __restrict__ ph, const int* __restrict__ batch,
    const float* __restrict__ lb1, const float* __restrict__ lw2,
    float* __restrict__ out) {
  __shared__ unsigned short As[4 * 128 * 8];  // 8 KB
  __shared__ unsigned short Bs[4 * 256 * 8];  // 16 KB
  int t = threadIdx.x;
  int j0 = blockIdx.x * MJ;
  int n0 = blockIdx.y * 128;
  int lane = t & 63;
  int wave = t >> 6;
  int wr = wave >> 1, wc = wave & 1;

  floatx4 acc[4][8];
#pragma unroll
  for (int a = 0; a < 4; ++a)
#pragma unroll
    for (int b = 0; b < 8; ++b) acc[a][b] = (floatx4){0.f, 0.f, 0.f, 0.f};

  // staging: A chunk c = t + 256p (p=0,1): row=c&127, kc=c>>7; B chunk c = t + 256p (p=0..3): col=t, kc=p
  int arow = n0 + (t & 127);
  if (arow >= NN) arow = NN - 1;
  const unsigned short* agp = xb + (size_t)arow * 384 + (t >> 7) * 8;
  const unsigned short* bgp = lw1tb + (size_t)(j0 + t) * 384;
  unsigned short* asb0 = As + (size_t)(wave * 64) * 8;
  unsigned short* asb1 = As + (size_t)(wave * 64 + 256) * 8;
  unsigned short* bsb[4];
#pragma unroll
  for (int p = 0; p < 4; ++p) bsb[p] = Bs + (size_t)(p * 256 + wave * 64) * 8;

  // prestage k0 = 0
  async16(asb0, agp);
  async16(asb1, agp + 16);
#pragma unroll
  for (int p = 0; p < 4; ++p) async16(bsb[p], bgp + p * 8);

  const unsigned short* afp = As + ((size_t)(lane >> 4) * 128 + wr * 64 + (lane & 15)) * 8;
  const unsigned short* bfp = Bs + ((size_t)(lane >> 4) * 256 + wc * 128 + (lane & 15)) * 8;

  for (int kk = 0; kk < 12; ++kk) {
    __syncthreads();  // drains vmcnt -> staged data valid
    short8 af[4], bf[8];
#pragma unroll
    for (int ti = 0; ti < 4; ++ti) af[ti] = *(const short8*)(afp + (size_t)ti * 16 * 8);
#pragma unroll
    for (int tj = 0; tj < 8; ++tj) bf[tj] = *(const short8*)(bfp + (size_t)tj * 16 * 8);
    __syncthreads();  // all frag reads done -> safe to overwrite
    if (kk < 11) {
      int k0 = (kk + 1) * 32;
      async16(asb0, agp + k0);
      async16(asb1, agp + k0 + 16);
#pragma unroll
      for (int p = 0; p < 4; ++p) async16(bsb[p], bgp + k0 + p * 8);
    }
#pragma unroll
    for (int ti = 0; ti < 4; ++ti)
#pragma unroll
      for (int tj = 0; tj < 8; ++tj)
        acc[ti][tj] = __builtin_amdgcn_mfma_f32_16x16x32_bf16(af[ti], bf[tj], acc[ti][tj], 0, 0, 0);
  }

  int colg = j0 + wc * 128 + (lane & 15);
#pragma unroll
  for (int ti = 0; ti < 4; ++ti) {
    int rowb = n0 + wr * 64 + ti * 16 + (lane >> 4) * 4;
#pragma unroll
    for (int r = 0; r < 4; ++r) {
      int row = rowb + r;
      int rc = (row < NN) ? row : 0;
      int bg = batch[rc];
      float partial = 0.f;
#pragma unroll
      for (int tj = 0; tj < 8; ++tj) {
        int j = colg + tj * 16;
        float v = acc[ti][tj][r] + ph[(size_t)bg * 512 + j] + lb1[j];
        partial += lrelu(v, 0.01f) * lw2[j];
      }
#pragma unroll
      for (int m = 1; m < 16; m <<= 1) partial += __shfl_xor(partial, m, 16);
      if ((lane & 15) == 0 && row < NN) atomicAdd(&out[row], partial);
    }
  }
}

extern "C" void kernel_launch(void* const* d_in, const int* in_sizes, int n_in,
                              void* d_out, int out_size, void* d_ws, size_t ws_size,
                              hipStream_t stream) {
  const float* x = (const float*)d_in[0];
  const int* edge_index = (const int*)d_in[1];
  const int* src = edge_index;
  const int* dstp = edge_index + NE;
  const float* edge_attr = (const float*)d_in[2];
  const int* batch = (const int*)d_in[3];
  const float* W[3] = {(const float*)d_in[4], (const float*)d_in[10], (const float*)d_in[16]};
  const float* as_[3] = {(const float*)d_in[5], (const float*)d_in[11], (const float*)d_in[17]};
  const float* ad_[3] = {(const float*)d_in[6], (const float*)d_in[12], (const float*)d_in[18]};
  const float* We_[3] = {(const float*)d_in[7], (const float*)d_in[13], (const float*)d_in[19]};
  const float* ae_[3] = {(const float*)d_in[8], (const float*)d_in[14], (const float*)d_in[20]};
  const float* b_[3] = {(const float*)d_in[9], (const float*)d_in[15], (const float*)d_in[21]};
  const float* lw1 = (const float*)d_in[22];
  const float* lb1 = (const float*)d_in[23];
  const float* lw2 = (const float*)d_in[24];
  const float* lb2 = (const float*)d_in[25];
  float* out = (float*)d_out;

  // workspace carve-up
  float* f = (float*)d_ws;
  size_t o = 0;  // in floats
  float* asrc = f + o;  o += (size_t)NN * NHEAD;
  float* adst = f + o;  o += (size_t)NN * NHEAD;
  float* wea = f + o;   o += 256;
  float* hpool = f + o; o += (size_t)NG * HC;
  float* ph = f + o;    o += (size_t)NG * 512;
  float* aep = f + o;   o += (size_t)3 * NE * 4;                     // [3][E][4] perm-ordered logits
  unsigned short* xb0 = (unsigned short*)(f + o);   o += (size_t)NN * DIN1 / 2;
  unsigned short* htb = (unsigned short*)(f + o);   o += (size_t)NN * HC / 2;
  unsigned short* xb = (unsigned short*)(f + o);    o += (size_t)NN * 384 / 2;
  unsigned short* wtb = (unsigned short*)(f + o);   o += (size_t)(128 * 64 + 2 * 128 * 128) / 2;
  unsigned short* lw1tb = (unsigned short*)(f + o); o += (512 * 384) / 2;
  unsigned short* wsdb = (unsigned short*)(f + o);  o += (size_t)(3 * 16 * 128) / 2;
  int* row_start = (int*)(f + o);
  int* cnt = row_start + (NN + 1);
  int* fill = cnt + NN;
  int* aux = fill + NN;
  int* gs = aux + 256;
  int* perm = gs + (NG + 1);
  int* srcp = perm + NE;

  const int NB = (NN + 255) / 256;
  const int EB = (NE + 255) / 256;

  hipMemsetAsync(cnt, 0, (size_t)2 * NN * sizeof(int), stream);  // cnt + fill

  k_we_a<<<1, 256, 0, stream>>>(We_[0], ae_[0], We_[1], ae_[1], We_[2], ae_[2], wea);
  k_wsd<<<(3 * 16 * 128 + 255) / 256, 256, 0, stream>>>(W[0], as_[0], ad_[0], W[1], as_[1], ad_[1],
                                                        W[2], as_[2], ad_[2], wsdb);
  k_lw1t<<<(512 * 384 + 255) / 256, 256, 0, stream>>>(lw1, lw1tb);
  k_wt<<<(128 * 64 + 2 * 128 * 128 + 255) / 256, 256, 0, stream>>>(W[0], W[1], W[2], wtb);
  k_cast<<<(NN * DIN1 + 255) / 256, 256, 0, stream>>>(x, xb0);
  k_hist<<<EB, 256, 0, stream>>>(dstp, cnt);
  k_scan1<<<NB, 256, 0, stream>>>(cnt, row_start, aux);
  k_scan2<<<1, 256, 0, stream>>>(aux, NB);
  k_scan3<<<NB, 256, 0, stream>>>(row_start, aux);
  k_scatter<<<EB, 256, 0, stream>>>(dstp, row_start, fill, perm);
  k_permute<<<EB, 256, 0, stream>>>(perm, src, edge_attr, wea, srcp, aep);
  k_gstart<<<NB, 256, 0, stream>>>(batch, gs);
  k_outinit<<<NB, 256, 0, stream>>>(out, lb2);

  const int CONVB = (NN + 127) / 128;
  unsigned short* wt_l[3] = {wtb, wtb + 128 * 64, wtb + 128 * 64 + 128 * 128};
  for (int l = 0; l < 3; ++l) {
    unsigned short* wsd_l = wsdb + (size_t)l * 16 * 128;
    if (l == 0)
      k_conv_mfma<64, 64><<<CONVB, 256, 0, stream>>>(xb0, wt_l[0], wsd_l, htb, asrc, adst);
    else if (l == 1)
      k_conv_mfma<128, 384><<<CONVB, 256, 0, stream>>>(xb, wt_l[1], wsd_l, htb, asrc, adst);
    else
      k_conv_mfma<128, 384><<<CONVB, 256, 0, stream>>>(xb + 128, wt_l[2], wsd_l, htb, asrc, adst);
    k_aggregate<<<(NN + 3) / 4, 256, 0, stream>>>(htb, srcp, aep + (size_t)l * NE * 4, asrc, adst,
                                                  row_start, b_[l], xb, l * HC);
  }

  k_pool<<<NG, 128, 0, stream>>>(xb, gs, hpool);
  k_pool_gemm<<<dim3(4, NG / 16), 256, 0, stream>>>(hpool, lw1, ph);
  k_mlp_mfma<<<dim3(2, (NN + 127) / 128), 256, 0, stream>>>(xb, lw1tb, ph, batch, lb1, lw2, out);
}

// Round 7
// 520.044 us; speedup vs baseline: 3.0398x; 1.0765x over previous
//
#include <hip/hip_runtime.h>
#include <hip/hip_bf16.h>
#include <math.h>

#define NN 50000
#define NNP 50048  // padded to multiple of 128
#define NE 800000
#define DIN1 64
#define NHEAD 4
#define CH 32
#define HC 128
#define EDIM 16
#define NG 2000
#define MAXCH 64  // edge chunk per node-wave

typedef __attribute__((ext_vector_type(8))) short short8;
typedef __attribute__((ext_vector_type(4))) float floatx4;

__device__ __forceinline__ float lrelu(float x, float s) { return x > 0.f ? x : s * x; }

__device__ __forceinline__ unsigned short f2bf(float x) {
  unsigned int u = __float_as_uint(x);
  u += 0x7fff + ((u >> 16) & 1);  // RNE
  return (unsigned short)(u >> 16);
}
__device__ __forceinline__ float bflo(unsigned int u) { return __uint_as_float(u << 16); }
__device__ __forceinline__ float bfhi(unsigned int u) { return __uint_as_float(u & 0xffff0000u); }

// async global->LDS: per-lane 16B from lane's own gptr; LDS dest = wave-uniform base + lane*16.
// CALLER passes per-lane g (consecutive lanes -> consecutive 16B chunks for coalescing).
__device__ __forceinline__ void async16(void* lds, const void* g) {
  __builtin_amdgcn_global_load_lds((const __attribute__((address_space(1))) unsigned int*)g,
                                   (__attribute__((address_space(3))) unsigned int*)lds, 16, 0, 0);
}

// ---------------- we_a precompute: we_a[l*64 + d*4 + h] = sum_c We_l[d, h*32+c]*ae_l[h,c]
__global__ __launch_bounds__(256) void k_we_a(
    const float* __restrict__ We1, const float* __restrict__ ae1,
    const float* __restrict__ We2, const float* __restrict__ ae2,
    const float* __restrict__ We3, const float* __restrict__ ae3,
    float* __restrict__ we_a) {
  int t = threadIdx.x;
  if (t >= 3 * EDIM * NHEAD) return;
  int l = t / (EDIM * NHEAD);
  int rem = t % (EDIM * NHEAD);
  int d = rem / NHEAD, h = rem % NHEAD;
  const float* We = (l == 0) ? We1 : ((l == 1) ? We2 : We3);
  const float* ae = (l == 0) ? ae1 : ((l == 1) ? ae2 : ae3);
  float s = 0.f;
  for (int c = 0; c < CH; ++c) s += We[d * HC + h * CH + c] * ae[h * CH + c];
  we_a[t] = s;
}

// ---------------- wsd image: [l][kc16][col16][8]; col<4: (W a_s)|head; 4..7: (W a_d); else 0
__global__ __launch_bounds__(256) void k_wsd(
    const float* __restrict__ W1, const float* __restrict__ as1, const float* __restrict__ ad1,
    const float* __restrict__ W2, const float* __restrict__ as2, const float* __restrict__ ad2,
    const float* __restrict__ W3, const float* __restrict__ as3, const float* __restrict__ ad3,
    unsigned short* __restrict__ wsdb) {
  int i = blockIdx.x * 256 + threadIdx.x;
  if (i >= 3 * 16 * 128) return;
  int l = i >> 11;
  int col = (i >> 7) & 15;
  int k = i & 127;
  size_t oidx = (size_t)l * 2048 + ((size_t)(k >> 3) * 16 + col) * 8 + (k & 7);
  if (col >= 8 || (l == 0 && k >= DIN1)) { wsdb[oidx] = 0; return; }
  const float* W = (l == 0) ? W1 : ((l == 1) ? W2 : W3);
  int head = col & 3;
  const float* av = (col < 4) ? ((l == 0) ? as1 : ((l == 1) ? as2 : as3))
                              : ((l == 0) ? ad1 : ((l == 1) ? ad2 : ad3));
  float s = 0.f;
  for (int c = 0; c < CH; ++c) s += W[(size_t)k * HC + head * CH + c] * av[head * CH + c];
  wsdb[oidx] = f2bf(s);
}

// ---------------- lw1 rows 0:384 -> image [jh2][kc48][col256][8]
__global__ __launch_bounds__(256) void k_lw1t(const float* __restrict__ lw1, unsigned short* __restrict__ lw1img) {
  int i = blockIdx.x * 256 + threadIdx.x;
  if (i >= 512 * 384) return;
  int j = i / 384, k = i % 384;
  int jh = j >> 8, jc = j & 255;
  lw1img[((size_t)jh * 48 * 256 + (size_t)(k >> 3) * 256 + jc) * 8 + (k & 7)] = f2bf(lw1[(size_t)k * 512 + j]);
}

// ---------------- W images: l1 [kc8][col128][8] @0; l2 [kc16][col128][8] @8192; l3 @24576
__global__ __launch_bounds__(256) void k_wt(const float* __restrict__ W1, const float* __restrict__ W2,
                                            const float* __restrict__ W3, unsigned short* __restrict__ wtb) {
  int i = blockIdx.x * 256 + threadIdx.x;
  if (i >= 128 * 64 + 2 * 128 * 128) return;
  const float* W;
  int j, k;
  size_t base;
  if (i < 128 * 64) {
    W = W1; j = i / 64; k = i % 64; base = 0;
  } else if (i < 128 * 64 + 128 * 128) {
    int ii = i - 128 * 64;
    W = W2; j = ii / 128; k = ii % 128; base = 8192;
  } else {
    int ii = i - (128 * 64 + 128 * 128);
    W = W3; j = ii / 128; k = ii % 128; base = 24576;
  }
  wtb[base + ((size_t)(k >> 3) * 128 + j) * 8 + (k & 7)] = f2bf(W[(size_t)k * HC + j]);
}

// ---------------- cast x fp32 -> XB0 k-major [kc8][NNP][8]
__global__ __launch_bounds__(256) void k_cast(const float* __restrict__ x, unsigned short* __restrict__ xb0) {
  int i = blockIdx.x * 256 + threadIdx.x;
  if (i >= NN * DIN1) return;
  int n = i >> 6, k = i & 63;
  xb0[((size_t)(k >> 3) * NNP + n) * 8 + (k & 7)] = f2bf(x[i]);
}

// ---------------- CSR build
__global__ __launch_bounds__(256) void k_hist(const int* __restrict__ dst, int* __restrict__ cnt) {
  int e = blockIdx.x * 256 + threadIdx.x;
  if (e < NE) atomicAdd(&cnt[dst[e]], 1);
}

__global__ __launch_bounds__(256) void k_scan1(const int* __restrict__ cnt, int* __restrict__ row_start,
                                               int* __restrict__ aux) {
  __shared__ int s[256];
  int t = threadIdx.x;
  int i = blockIdx.x * 256 + t;
  int v = (i < NN) ? cnt[i] : 0;
  s[t] = v;
  __syncthreads();
  for (int off = 1; off < 256; off <<= 1) {
    int tv = (t >= off) ? s[t - off] : 0;
    __syncthreads();
    s[t] += tv;
    __syncthreads();
  }
  if (i < NN) row_start[i] = s[t] - v;
  if (t == 255) aux[blockIdx.x] = s[255];
}

__global__ __launch_bounds__(256) void k_scan2(int* __restrict__ aux, int nb) {
  __shared__ int s[256];
  int t = threadIdx.x;
  int v = (t < nb) ? aux[t] : 0;
  s[t] = v;
  __syncthreads();
  for (int off = 1; off < 256; off <<= 1) {
    int tv = (t >= off) ? s[t - off] : 0;
    __syncthreads();
    s[t] += tv;
    __syncthreads();
  }
  if (t < nb) aux[t] = s[t] - v;
}

__global__ __launch_bounds__(256) void k_scan3(int* __restrict__ row_start, const int* __restrict__ aux) {
  int i = blockIdx.x * 256 + threadIdx.x;
  if (i < NN) row_start[i] += aux[i >> 8];
  else if (i == NN) row_start[NN] = NE;
}

// ---------------- scatter: index only
__global__ __launch_bounds__(256) void k_scatter(const int* __restrict__ dst, const int* __restrict__ row_start,
                                                 int* __restrict__ fill, int* __restrict__ perm) {
  int e = blockIdx.x * 256 + threadIdx.x;
  if (e >= NE) return;
  int d = dst[e];
  int p = atomicAdd(&fill[d], 1);
  perm[row_start[d] + p] = e;
}

// ---------------- permute: stream pos, gather e=perm[pos], write srcp + 3 aep planes coalesced
__global__ __launch_bounds__(256) void k_permute(const int* __restrict__ perm, const int* __restrict__ src,
                                                 const float* __restrict__ edge_attr, const float* __restrict__ wea,
                                                 int* __restrict__ srcp, float* __restrict__ aep) {
  __shared__ float wl[3 * EDIM * NHEAD];
  int t = threadIdx.x;
  if (t < 3 * EDIM * NHEAD) wl[t] = wea[t];
  __syncthreads();
  int pos = blockIdx.x * 256 + t;
  if (pos >= NE) return;
  int e = perm[pos];
  srcp[pos] = src[e];
  float ea[EDIM];
#pragma unroll
  for (int k = 0; k < EDIM; k += 4) {
    float4 v = *(const float4*)&edge_attr[(size_t)e * EDIM + k];
    ea[k] = v.x; ea[k + 1] = v.y; ea[k + 2] = v.z; ea[k + 3] = v.w;
  }
#pragma unroll
  for (int l = 0; l < 3; ++l) {
    float a0 = 0.f, a1 = 0.f, a2 = 0.f, a3 = 0.f;
#pragma unroll
    for (int k = 0; k < EDIM; ++k) {
      float ev = ea[k];
      a0 += ev * wl[l * 64 + k * 4 + 0];
      a1 += ev * wl[l * 64 + k * 4 + 1];
      a2 += ev * wl[l * 64 + k * 4 + 2];
      a3 += ev * wl[l * 64 + k * 4 + 3];
    }
    *(float4*)&aep[(size_t)l * NE * 4 + (size_t)pos * 4] = make_float4(a0, a1, a2, a3);
  }
}

// ---------------- graph ranges (batch is sorted)
__global__ __launch_bounds__(256) void k_gstart(const int* __restrict__ batch, int* __restrict__ gs) {
  int i = blockIdx.x * 256 + threadIdx.x;
  if (i >= NN) return;
  int b = batch[i];
  if (i == 0) {
    for (int g = 0; g <= b; ++g) gs[g] = 0;
  } else {
    int pb = batch[i - 1];
    for (int g = pb + 1; g <= b; ++g) gs[g] = i;
  }
  if (i == NN - 1) {
    for (int g = b + 1; g <= NG; ++g) gs[g] = NN;
  }
}

// ---------------- conv GEMM via MFMA, chunk-linear LDS, coalesced async16 staging.
// xin: k-major [kc][NNP][8] slice base. wt: image [kc][128][8]. wsd: image [kc][16][8].
template <int K>
__global__ __launch_bounds__(256) void k_conv_mfma(const unsigned short* __restrict__ xin,
                                                   const unsigned short* __restrict__ wt,
                                                   const unsigned short* __restrict__ wsd,
                                                   unsigned short* __restrict__ htb,
                                                   float* __restrict__ asrc, float* __restrict__ adst) {
  __shared__ unsigned short As[512 * 8];   // [kc4][row128]
  __shared__ unsigned short Bs[512 * 8];   // [kc4][col128]
  __shared__ unsigned short Bs2[64 * 8];   // [kc4][16]
  int t = threadIdx.x;
  int n0 = blockIdx.x * 128;
  int lane = t & 63;
  int wave = t >> 6;
  int wr = wave >> 1, wc = wave & 1;
  int kadd = wave >> 1, rb = (wave & 1) * 64;  // staging decomposition

  floatx4 acc[4][4];
  floatx4 acce[4];
#pragma unroll
  for (int a = 0; a < 4; ++a) {
    acce[a] = (floatx4){0.f, 0.f, 0.f, 0.f};
#pragma unroll
    for (int b = 0; b < 4; ++b) acc[a][b] = (floatx4){0.f, 0.f, 0.f, 0.f};
  }

  const unsigned short* afp = As + ((size_t)(lane >> 4) * 128 + wr * 64 + (lane & 15)) * 8;
  const unsigned short* bfp = Bs + ((size_t)(lane >> 4) * 128 + wc * 64 + (lane & 15)) * 8;
  const unsigned short* b2fp = Bs2 + ((size_t)(lane >> 4) * 16 + (lane & 15)) * 8;

  // prestage kk=0 (kb=0). NOTE: global ptr is per-lane (+lane); LDS side auto-adds lane*16.
#pragma unroll
  for (int p = 0; p < 2; ++p) {
    async16(As + (size_t)(p * 256 + wave * 64) * 8,
            xin + ((size_t)(p * 2 + kadd) * NNP + n0 + rb + lane) * 8);
    async16(Bs + (size_t)(p * 256 + wave * 64) * 8,
            wt + ((size_t)(p * 2 + kadd) * 128 + rb + lane) * 8);
  }
  if (wave == 0) async16(Bs2, wsd + (size_t)lane * 8);

  for (int kk = 0; kk < K / 32; ++kk) {
    __syncthreads();  // vmcnt drained: staged data valid
    short8 af[4], bf[4], bf2;
#pragma unroll
    for (int ti = 0; ti < 4; ++ti) af[ti] = *(const short8*)(afp + (size_t)ti * 16 * 8);
#pragma unroll
    for (int tj = 0; tj < 4; ++tj) bf[tj] = *(const short8*)(bfp + (size_t)tj * 16 * 8);
    bf2 = *(const short8*)(b2fp);
    __syncthreads();  // frag reads done -> safe to overwrite
    if (kk < K / 32 - 1) {
      int kb = (kk + 1) * 4;
#pragma unroll
      for (int p = 0; p < 2; ++p) {
        async16(As + (size_t)(p * 256 + wave * 64) * 8,
                xin + ((size_t)(kb + p * 2 + kadd) * NNP + n0 + rb + lane) * 8);
        async16(Bs + (size_t)(p * 256 + wave * 64) * 8,
                wt + ((size_t)(kb + p * 2 + kadd) * 128 + rb + lane) * 8);
      }
      if (wave == 0) async16(Bs2, wsd + ((size_t)kb * 16 + lane) * 8);
    }
#pragma unroll
    for (int ti = 0; ti < 4; ++ti)
#pragma unroll
      for (int tj = 0; tj < 4; ++tj)
        acc[ti][tj] = __builtin_amdgcn_mfma_f32_16x16x32_bf16(af[ti], bf[tj], acc[ti][tj], 0, 0, 0);
    if (wc == 0) {
#pragma unroll
      for (int ti = 0; ti < 4; ++ti)
        acce[ti] = __builtin_amdgcn_mfma_f32_16x16x32_bf16(af[ti], bf2, acce[ti], 0, 0, 0);
    }
  }

  int q = lane & 15;
  int colg = wc * 64 + q;
#pragma unroll
  for (int ti = 0; ti < 4; ++ti) {
    int rowb = n0 + wr * 64 + ti * 16 + (lane >> 4) * 4;
#pragma unroll
    for (int r = 0; r < 4; ++r) {
      int row = rowb + r;
      if (row < NN) {
        htb[(size_t)row * HC + colg] = f2bf(acc[ti][0][r]);
        htb[(size_t)row * HC + colg + 16] = f2bf(acc[ti][1][r]);
        htb[(size_t)row * HC + colg + 32] = f2bf(acc[ti][2][r]);
        htb[(size_t)row * HC + colg + 48] = f2bf(acc[ti][3][r]);
        if (wc == 0 && q < 8) {
          float v = acce[ti][r];
          if (q < 4) asrc[row * 4 + q] = v;
          else adst[row * 4 + (q - 4)] = v;
        }
      }
    }
  }
}

// ---------------- fused alpha + softmax + aggregate. One wave per node. 2x-unrolled gather.
// Writes k-major XB chunks [kcoff+q][n][8].
__global__ __launch_bounds__(256) void k_aggregate(
    const unsigned short* __restrict__ htb, const int* __restrict__ srcp,
    const float* __restrict__ aep, const float* __restrict__ asrc, const float* __restrict__ adst,
    const int* __restrict__ row_start, const float* __restrict__ bias,
    unsigned short* __restrict__ XBp, int kcoff) {
  __shared__ float exs[4][MAXCH][4];
  __shared__ int cns[4];
  int t = threadIdx.x;
  int lane = t & 63, wid = t >> 6;
  int n = blockIdx.x * 4 + wid;
  bool nok = n < NN;
  int rs = nok ? row_start[n] : 0;
  int re = nok ? row_start[n + 1] : 0;
  int deg = re - rs;
  if (lane == 0) cns[wid] = (deg + MAXCH - 1) / MAXCH;
  __syncthreads();
  int maxc = max(max(cns[0], cns[1]), max(cns[2], cns[3]));
  int q = lane & 15, g = lane >> 4;
  int h = q >> 2;
  float4 ad4 = nok ? *(const float4*)&adst[n * 4] : make_float4(0.f, 0.f, 0.f, 0.f);
  float acc[8];
#pragma unroll
  for (int j = 0; j < 8; ++j) acc[j] = 0.f;
  float d0 = 0.f, d1 = 0.f, d2 = 0.f, d3 = 0.f;

  for (int cc = 0; cc < maxc; ++cc) {
    int base = rs + cc * MAXCH;
    int m = re - base;
    if (m > MAXCH) m = MAXCH;
    if (lane < m) {
      int i = base + lane;
      int s = srcp[i];
      float4 ae = *(const float4*)&aep[(size_t)i * 4];
      float4 as4 = *(const float4*)&asrc[s * 4];
      float4 ex;
      ex.x = __expf(lrelu(as4.x + ad4.x + ae.x, 0.2f));
      ex.y = __expf(lrelu(as4.y + ad4.y + ae.y, 0.2f));
      ex.z = __expf(lrelu(as4.z + ad4.z + ae.z, 0.2f));
      ex.w = __expf(lrelu(as4.w + ad4.w + ae.w, 0.2f));
      *(float4*)&exs[wid][lane][0] = ex;
      d0 += ex.x; d1 += ex.y; d2 += ex.z; d3 += ex.w;
    }
    __syncthreads();
    int iters = (m > 0) ? ((m + 7) >> 3) : 0;
    for (int kk = 0; kk < iters; ++kk) {
      int ii0 = kk * 8 + g;
      int ii1 = ii0 + 4;
      int i0 = base + ((ii0 < m) ? ii0 : 0);
      int i1 = base + ((ii1 < m) ? ii1 : 0);
      int s0 = srcp[i0];
      int s1 = srcp[i1];
      uint4 h0 = *(const uint4*)(htb + (size_t)s0 * HC + q * 8);
      uint4 h1 = *(const uint4*)(htb + (size_t)s1 * HC + q * 8);
      float w0 = (ii0 < m) ? exs[wid][ii0][h] : 0.f;
      float w1 = (ii1 < m) ? exs[wid][ii1][h] : 0.f;
      acc[0] += w0 * bflo(h0.x) + w1 * bflo(h1.x);
      acc[1] += w0 * bfhi(h0.x) + w1 * bfhi(h1.x);
      acc[2] += w0 * bflo(h0.y) + w1 * bflo(h1.y);
      acc[3] += w0 * bfhi(h0.y) + w1 * bfhi(h1.y);
      acc[4] += w0 * bflo(h0.z) + w1 * bflo(h1.z);
      acc[5] += w0 * bfhi(h0.z) + w1 * bfhi(h1.z);
      acc[6] += w0 * bflo(h0.w) + w1 * bflo(h1.w);
      acc[7] += w0 * bfhi(h0.w) + w1 * bfhi(h1.w);
    }
    __syncthreads();
  }

#pragma unroll
  for (int mm = 1; mm < 64; mm <<= 1) {
    d0 += __shfl_xor(d0, mm, 64);
    d1 += __shfl_xor(d1, mm, 64);
    d2 += __shfl_xor(d2, mm, 64);
    d3 += __shfl_xor(d3, mm, 64);
  }
#pragma unroll
  for (int j = 0; j < 8; ++j) {
    acc[j] += __shfl_xor(acc[j], 16, 64);
    acc[j] += __shfl_xor(acc[j], 32, 64);
  }
  if (nok && g == 0) {
    float dh = (h == 0) ? d0 : ((h == 1) ? d1 : ((h == 2) ? d2 : d3));
    float inv = 1.f / (dh + 1e-16f);
    unsigned int w[4];
#pragma unroll
    for (int j = 0; j < 4; ++j) {
      float v0 = acc[2 * j] * inv + bias[q * 8 + 2 * j];
      float v1 = acc[2 * j + 1] * inv + bias[q * 8 + 2 * j + 1];
      w[j] = (unsigned int)f2bf(v0) | ((unsigned int)f2bf(v1) << 16);
    }
    *(uint4*)&XBp[((size_t)(kcoff + q) * NNP + n) * 8] = make_uint4(w[0], w[1], w[2], w[3]);
  }
}

// ---------------- global add pool from XB kc 32..47 (= h3)
__global__ __launch_bounds__(128) void k_pool(const unsigned short* __restrict__ XBp, const int* __restrict__ gs,
                                              float* __restrict__ hpool) {
  int g = blockIdx.x;
  int j = threadIdx.x;
  int kc = 32 + (j >> 3), sb = j & 7;
  int s = gs[g], e = gs[g + 1];
  float acc = 0.f;
  for (int i = s; i < e; ++i) acc += bflo((unsigned int)XBp[((size_t)kc * NNP + i) * 8 + sb]);
  hpool[(size_t)g * HC + j] = acc;
}

// ---------------- ph[g,0:512] = hpool[g,0:128] @ lw1[384:512, 0:512]
__global__ __launch_bounds__(256) void k_pool_gemm(const float* __restrict__ hpool, const float* __restrict__ lw1,
                                                   float* __restrict__ ph) {
  __shared__ float hp[16][128];
  int t = threadIdx.x;
  int j0 = blockIdx.x * 128;
  int g0 = blockIdx.y * 16;
  int jj = t & 127, gg = t >> 7;
#pragma unroll
  for (int i = 0; i < 8; ++i) {
    int q = t + 256 * i;
    int row = q >> 7, col = q & 127;
    hp[row][col] = hpool[(size_t)(g0 + row) * HC + col];
  }
  __syncthreads();
  float acc[8];
#pragma unroll
  for (int i = 0; i < 8; ++i) acc[i] = 0.f;
  for (int k = 0; k < HC; ++k) {
    float wv = lw1[(size_t)(384 + k) * 512 + j0 + jj];
#pragma unroll
    for (int gi = 0; gi < 8; ++gi) acc[gi] += hp[gg + 2 * gi][k] * wv;
  }
#pragma unroll
  for (int gi = 0; gi < 8; ++gi) ph[(size_t)(g0 + gg + 2 * gi) * 512 + j0 + jj] = acc[gi];
}

__global__ __launch_bounds__(256) void k_outinit(float* __restrict__ out, const float* __restrict__ lb2) {
  int i = blockIdx.x * 256 + threadIdx.x;
  if (i < NN) out[i] = lb2[0];
}

// ---------------- fused MLP via bf16 MFMA, coalesced async16, chunk-linear LDS.
// Tile 128 rows x 256 cols; 4 waves 2x2; acc 4x8.
__global__ __launch_bounds__(256, 2) void k_mlp_mfma(
    const unsigned short* __restrict__ XBp, const unsigned short* __restrict__ lw1img,
    const float* __restrict__ ph, const int* __restrict__ batch,
    const float* __restrict__ lb1, const float* __restrict__ lw2,
    float* __restrict__ out) {
  __shared__ unsigned short As[512 * 8];    // [kc4][row128]
  __shared__ unsigned short Bs[1024 * 8];   // [kc4][col256]
  int t = threadIdx.x;
  int jh = blockIdx.x;         // 0,1
  int n0 = blockIdx.y * 128;
  int lane = t & 63;
  int wave = t >> 6;
  int wr = wave >> 1, wc = wave & 1;
  int kadd = wave >> 1, rb = (wave & 1) * 64;
  const unsigned short* bimg = lw1img + (size_t)jh * 48 * 256 * 8;

  floatx4 acc[4][8];
#pragma unroll
  for (int a = 0; a < 4; ++a)
#pragma unroll
    for (int b = 0; b < 8; ++b) acc[a][b] = (floatx4){0.f, 0.f, 0.f, 0.f};

  const unsigned short* afp = As + ((size_t)(lane >> 4) * 128 + wr * 64 + (lane & 15)) * 8;
  const unsigned short* bfp = Bs + ((size_t)(lane >> 4) * 256 + wc * 128 + (lane & 15)) * 8;

  // prestage kk=0 (per-lane global ptrs)
#pragma unroll
  for (int p = 0; p < 2; ++p)
    async16(As + (size_t)(p * 256 + wave * 64) * 8,
            XBp + ((size_t)(p * 2 + kadd) * NNP + n0 + rb + lane) * 8);
#pragma unroll
  for (int p = 0; p < 4; ++p)
    async16(Bs + (size_t)(p * 256 + wave * 64) * 8,
            bimg + ((size_t)p * 256 + wave * 64 + lane) * 8);

  for (int kk = 0; kk < 12; ++kk) {
    __syncthreads();  // staged data valid
    short8 af[4], bf[8];
#pragma unroll
    for (int ti = 0; ti < 4; ++ti) af[ti] = *(const short8*)(afp + (size_t)ti * 16 * 8);
#pragma unroll
    for (int tj = 0; tj < 8; ++tj) bf[tj] = *(const short8*)(bfp + (size_t)tj * 16 * 8);
    __syncthreads();  // frag reads done
    if (kk < 11) {
      int kb = (kk + 1) * 4;
#pragma unroll
      for (int p = 0; p < 2; ++p)
        async16(As + (size_t)(p * 256 + wave * 64) * 8,
                XBp + ((size_t)(kb + p * 2 + kadd) * NNP + n0 + rb + lane) * 8);
#pragma unroll
      for (int p = 0; p < 4; ++p)
        async16(Bs + (size_t)(p * 256 + wave * 64) * 8,
                bimg + ((size_t)(kb + p) * 256 + wave * 64 + lane) * 8);
    }
#pragma unroll
    for (int ti = 0; ti < 4; ++ti)
#pragma unroll
      for (int tj = 0; tj < 8; ++tj)
        acc[ti][tj] = __builtin_amdgcn_mfma_f32_16x16x32_bf16(af[ti], bf[tj], acc[ti][tj], 0, 0, 0);
  }

  int colg = jh * 256 + wc * 128 + (lane & 15);
#pragma unroll
  for (int ti = 0; ti < 4; ++ti) {
    int rowb = n0 + wr * 64 + ti * 16 + (lane >> 4) * 4;
#pragma unroll
    for (int r = 0; r < 4; ++r) {
      int row = rowb + r;
      int rc = (row < NN) ? row : 0;
      int bg = batch[rc];
      float partial = 0.f;
#pragma unroll
      for (int tj = 0; tj < 8; ++tj) {
        int j = colg + tj * 16;
        float v = acc[ti][tj][r] + ph[(size_t)bg * 512 + j] + lb1[j];
        partial += lrelu(v, 0.01f) * lw2[j];
      }
#pragma unroll
      for (int m = 1; m < 16; m <<= 1) partial += __shfl_xor(partial, m, 16);
      if ((lane & 15) == 0 && row < NN) atomicAdd(&out[row], partial);
    }
  }
}

extern "C" void kernel_launch(void* const* d_in, const int* in_sizes, int n_in,
                              void* d_out, int out_size, void* d_ws, size_t ws_size,
                              hipStream_t stream) {
  const float* x = (const float*)d_in[0];
  const int* edge_index = (const int*)d_in[1];
  const int* src = edge_index;
  const int* dstp = edge_index + NE;
  const float* edge_attr = (const float*)d_in[2];
  const int* batch = (const int*)d_in[3];
  const float* W[3] = {(const float*)d_in[4], (const float*)d_in[10], (const float*)d_in[16]};
  const float* as_[3] = {(const float*)d_in[5], (const float*)d_in[11], (const float*)d_in[17]};
  const float* ad_[3] = {(const float*)d_in[6], (const float*)d_in[12], (const float*)d_in[18]};
  const float* We_[3] = {(const float*)d_in[7], (const float*)d_in[13], (const float*)d_in[19]};
  const float* ae_[3] = {(const float*)d_in[8], (const float*)d_in[14], (const float*)d_in[20]};
  const float* b_[3] = {(const float*)d_in[9], (const float*)d_in[15], (const float*)d_in[21]};
  const float* lw1 = (const float*)d_in[22];
  const float* lb1 = (const float*)d_in[23];
  const float* lw2 = (const float*)d_in[24];
  const float* lb2 = (const float*)d_in[25];
  float* out = (float*)d_out;

  // workspace carve-up (floats unless noted)
  float* f = (float*)d_ws;
  size_t o = 0;
  float* asrc = f + o;  o += (size_t)NN * NHEAD;
  float* adst = f + o;  o += (size_t)NN * NHEAD;
  float* wea = f + o;   o += 256;
  float* hpool = f + o; o += (size_t)NG * HC;
  float* aep = f + o;   o += (size_t)3 * NE * 4;
  // xb0 (k-major [8][NNP][8] bf16) overlaid with ph (fp32 [NG][512]): xb0 dead before ph written
  unsigned short* xb0 = (unsigned short*)(f + o);
  float* ph = (float*)xb0;
  o += (size_t)8 * NNP * 8 / 2;                                   // 1,601,536 floats > NG*512
  unsigned short* htb = (unsigned short*)(f + o);   o += (size_t)NN * HC / 2;
  unsigned short* XB = (unsigned short*)(f + o);    o += (size_t)48 * NNP * 8 / 2;
  unsigned short* wtb = (unsigned short*)(f + o);   o += (size_t)(128 * 64 + 2 * 128 * 128) / 2;
  unsigned short* lw1img = (unsigned short*)(f + o); o += (size_t)2 * 48 * 256 * 8 / 2;
  unsigned short* wsdb = (unsigned short*)(f + o);  o += (size_t)3 * 2048 / 2;
  int* row_start = (int*)(f + o);
  int* cnt = row_start + (NN + 1);
  int* fill = cnt + NN;
  int* aux = fill + NN;
  int* gs = aux + 256;
  int* perm = gs + (NG + 1);
  int* srcp = perm + NE;

  const int NB = (NN + 255) / 256;
  const int EB = (NE + 255) / 256;

  hipMemsetAsync(cnt, 0, (size_t)2 * NN * sizeof(int), stream);  // cnt + fill

  k_we_a<<<1, 256, 0, stream>>>(We_[0], ae_[0], We_[1], ae_[1], We_[2], ae_[2], wea);
  k_wsd<<<(3 * 16 * 128 + 255) / 256, 256, 0, stream>>>(W[0], as_[0], ad_[0], W[1], as_[1], ad_[1],
                                                        W[2], as_[2], ad_[2], wsdb);
  k_lw1t<<<(512 * 384 + 255) / 256, 256, 0, stream>>>(lw1, lw1img);
  k_wt<<<(128 * 64 + 2 * 128 * 128 + 255) / 256, 256, 0, stream>>>(W[0], W[1], W[2], wtb);
  k_cast<<<(NN * DIN1 + 255) / 256, 256, 0, stream>>>(x, xb0);
  k_hist<<<EB, 256, 0, stream>>>(dstp, cnt);
  k_scan1<<<NB, 256, 0, stream>>>(cnt, row_start, aux);
  k_scan2<<<1, 256, 0, stream>>>(aux, NB);
  k_scan3<<<NB, 256, 0, stream>>>(row_start, aux);
  k_scatter<<<EB, 256, 0, stream>>>(dstp, row_start, fill, perm);
  k_permute<<<EB, 256, 0, stream>>>(perm, src, edge_attr, wea, srcp, aep);
  k_gstart<<<NB, 256, 0, stream>>>(batch, gs);
  k_outinit<<<NB, 256, 0, stream>>>(out, lb2);

  const int CONVB = NNP / 128;  // 391
  unsigned short* wt_l[3] = {wtb, wtb + 8192, wtb + 24576};
  for (int l = 0; l < 3; ++l) {
    unsigned short* wsd_l = wsdb + (size_t)l * 2048;
    const unsigned short* xin = (l == 0) ? xb0 : (XB + (size_t)(l - 1) * 16 * NNP * 8);
    if (l == 0)
      k_conv_mfma<64><<<CONVB, 256, 0, stream>>>(xin, wt_l[0], wsd_l, htb, asrc, adst);
    else
      k_conv_mfma<128><<<CONVB, 256, 0, stream>>>(xin, wt_l[l], wsd_l, htb, asrc, adst);
    k_aggregate<<<(NN + 3) / 4, 256, 0, stream>>>(htb, srcp, aep + (size_t)l * NE * 4, asrc, adst,
                                                  row_start, b_[l], XB, l * 16);
  }

  k_pool<<<NG, 128, 0, stream>>>(XB, gs, hpool);
  k_pool_gemm<<<dim3(4, NG / 16), 256, 0, stream>>>(hpool, lw1, ph);
  k_mlp_mfma<<<dim3(2, NNP / 128), 256, 0, stream>>>(XB, lw1img, ph, batch, lb1, lw2, out);
}

// Round 9
// 485.702 us; speedup vs baseline: 3.2547x; 1.0707x over previous
//
#include <hip/hip_runtime.h>
#include <hip/hip_bf16.h>
#include <math.h>

#define NN 50000
#define NNP 50048  // padded to multiple of 128
#define NE 800000
#define DIN1 64
#define NHEAD 4
#define CH 32
#define HC 128
#define EDIM 16
#define NG 2000
#define MAXCH 64  // edge chunk per node-wave

typedef __attribute__((ext_vector_type(8))) short short8;
typedef __attribute__((ext_vector_type(4))) float floatx4;

__device__ __forceinline__ float lrelu(float x, float s) { return x > 0.f ? x : s * x; }

__device__ __forceinline__ unsigned short f2bf(float x) {
  unsigned int u = __float_as_uint(x);
  u += 0x7fff + ((u >> 16) & 1);  // RNE
  return (unsigned short)(u >> 16);
}
__device__ __forceinline__ float bflo(unsigned int u) { return __uint_as_float(u << 16); }
__device__ __forceinline__ float bfhi(unsigned int u) { return __uint_as_float(u & 0xffff0000u); }

// async global->LDS: per-lane 16B from lane's own gptr; LDS dest = wave-uniform base + lane*16.
__device__ __forceinline__ void async16(void* lds, const void* g) {
  __builtin_amdgcn_global_load_lds((const __attribute__((address_space(1))) unsigned int*)g,
                                   (__attribute__((address_space(3))) unsigned int*)lds, 16, 0, 0);
}

// ================= merged prep kernel: we_a | wsd | lw1t | wt | cast | gstart | outinit | hist
#define NB_WEA 1
#define NB_WSD 24
#define NB_LW1T 768
#define NB_WT 160
#define NB_CAST 12500
#define NB_GST 196
#define NB_OUT 196
#define NB_HIST 3125
#define PREP_BLOCKS (NB_WEA + NB_WSD + NB_LW1T + NB_WT + NB_CAST + NB_GST + NB_OUT + NB_HIST)

__global__ __launch_bounds__(256) void k_prep(
    const float* __restrict__ We1, const float* __restrict__ ae1,
    const float* __restrict__ We2, const float* __restrict__ ae2,
    const float* __restrict__ We3, const float* __restrict__ ae3, float* __restrict__ wea,
    const float* __restrict__ W1, const float* __restrict__ as1, const float* __restrict__ ad1,
    const float* __restrict__ W2, const float* __restrict__ as2, const float* __restrict__ ad2,
    const float* __restrict__ W3, const float* __restrict__ as3, const float* __restrict__ ad3,
    unsigned short* __restrict__ wsdb,
    const float* __restrict__ lw1, unsigned short* __restrict__ lw1img,
    unsigned short* __restrict__ wtb,
    const float* __restrict__ x, unsigned short* __restrict__ xb0,
    const int* __restrict__ batch, int* __restrict__ gs,
    float* __restrict__ out, const float* __restrict__ lb2,
    const int* __restrict__ dstp, int* __restrict__ cnt) {
  int b = blockIdx.x;
  int t = threadIdx.x;
  if (b < NB_WEA) {
    if (t >= 3 * EDIM * NHEAD) return;
    int l = t / (EDIM * NHEAD);
    int rem = t % (EDIM * NHEAD);
    int d = rem / NHEAD, h = rem % NHEAD;
    const float* We = (l == 0) ? We1 : ((l == 1) ? We2 : We3);
    const float* ae = (l == 0) ? ae1 : ((l == 1) ? ae2 : ae3);
    float s = 0.f;
    for (int c = 0; c < CH; ++c) s += We[d * HC + h * CH + c] * ae[h * CH + c];
    wea[t] = s;
    return;
  }
  b -= NB_WEA;
  if (b < NB_WSD) {
    int i = b * 256 + t;
    int l = i >> 11;
    int col = (i >> 7) & 15;
    int k = i & 127;
    size_t oidx = (size_t)l * 2048 + ((size_t)(k >> 3) * 16 + col) * 8 + (k & 7);
    if (col >= 8 || (l == 0 && k >= DIN1)) { wsdb[oidx] = 0; return; }
    const float* W = (l == 0) ? W1 : ((l == 1) ? W2 : W3);
    int head = col & 3;
    const float* av = (col < 4) ? ((l == 0) ? as1 : ((l == 1) ? as2 : as3))
                                : ((l == 0) ? ad1 : ((l == 1) ? ad2 : ad3));
    float s = 0.f;
    for (int c = 0; c < CH; ++c) s += W[(size_t)k * HC + head * CH + c] * av[head * CH + c];
    wsdb[oidx] = f2bf(s);
    return;
  }
  b -= NB_WSD;
  if (b < NB_LW1T) {
    int i = b * 256 + t;
    int j = i / 384, k = i % 384;
    int jh = j >> 8, jc = j & 255;
    lw1img[((size_t)jh * 48 * 256 + (size_t)(k >> 3) * 256 + jc) * 8 + (k & 7)] =
        f2bf(lw1[(size_t)k * 512 + j]);
    return;
  }
  b -= NB_LW1T;
  if (b < NB_WT) {
    int i = b * 256 + t;
    const float* W;
    int j, k;
    size_t base;
    if (i < 128 * 64) {
      W = W1; j = i / 64; k = i % 64; base = 0;
    } else if (i < 128 * 64 + 128 * 128) {
      int ii = i - 128 * 64;
      W = W2; j = ii / 128; k = ii % 128; base = 8192;
    } else {
      int ii = i - (128 * 64 + 128 * 128);
      W = W3; j = ii / 128; k = ii % 128; base = 24576;
    }
    wtb[base + ((size_t)(k >> 3) * 128 + j) * 8 + (k & 7)] = f2bf(W[(size_t)k * HC + j]);
    return;
  }
  b -= NB_WT;
  if (b < NB_CAST) {
    int i = b * 256 + t;
    int n = i >> 6, k = i & 63;
    xb0[((size_t)(k >> 3) * NNP + n) * 8 + (k & 7)] = f2bf(x[i]);
    return;
  }
  b -= NB_CAST;
  if (b < NB_GST) {
    int i = b * 256 + t;
    if (i >= NN) return;
    int bb = batch[i];
    if (i == 0) {
      for (int g = 0; g <= bb; ++g) gs[g] = 0;
    } else {
      int pb = batch[i - 1];
      for (int g = pb + 1; g <= bb; ++g) gs[g] = i;
    }
    if (i == NN - 1) {
      for (int g = bb + 1; g <= NG; ++g) gs[g] = NN;
    }
    return;
  }
  b -= NB_GST;
  if (b < NB_OUT) {
    int i = b * 256 + t;
    if (i < NN) out[i] = lb2[0];
    return;
  }
  b -= NB_OUT;
  {
    int e = b * 256 + t;
    if (e < NE) atomicAdd(&cnt[dstp[e]], 1);
  }
}

// ---------------- CSR scans
__global__ __launch_bounds__(256) void k_scan1(const int* __restrict__ cnt, int* __restrict__ row_start,
                                               int* __restrict__ aux) {
  __shared__ int s[256];
  int t = threadIdx.x;
  int i = blockIdx.x * 256 + t;
  int v = (i < NN) ? cnt[i] : 0;
  s[t] = v;
  __syncthreads();
  for (int off = 1; off < 256; off <<= 1) {
    int tv = (t >= off) ? s[t - off] : 0;
    __syncthreads();
    s[t] += tv;
    __syncthreads();
  }
  if (i < NN) row_start[i] = s[t] - v;
  if (t == 255) aux[blockIdx.x] = s[255];
}

__global__ __launch_bounds__(256) void k_scan2(int* __restrict__ aux, int nb) {
  __shared__ int s[256];
  int t = threadIdx.x;
  int v = (t < nb) ? aux[t] : 0;
  s[t] = v;
  __syncthreads();
  for (int off = 1; off < 256; off <<= 1) {
    int tv = (t >= off) ? s[t - off] : 0;
    __syncthreads();
    s[t] += tv;
    __syncthreads();
  }
  if (t < nb) aux[t] = s[t] - v;
}

__global__ __launch_bounds__(256) void k_scan3(int* __restrict__ row_start, const int* __restrict__ aux) {
  int i = blockIdx.x * 256 + threadIdx.x;
  if (i < NN) row_start[i] += aux[i >> 8];
  else if (i == NN) row_start[NN] = NE;
}

// ---------------- scatter: index only
__global__ __launch_bounds__(256) void k_scatter(const int* __restrict__ dst, const int* __restrict__ row_start,
                                                 int* __restrict__ fill, int* __restrict__ perm) {
  int e = blockIdx.x * 256 + threadIdx.x;
  if (e >= NE) return;
  int d = dst[e];
  int p = atomicAdd(&fill[d], 1);
  perm[row_start[d] + p] = e;
}

// ---------------- permute: stream pos, gather e=perm[pos], write srcp + 3 aep planes coalesced
__global__ __launch_bounds__(256) void k_permute(const int* __restrict__ perm, const int* __restrict__ src,
                                                 const float* __restrict__ edge_attr, const float* __restrict__ wea,
                                                 int* __restrict__ srcp, float* __restrict__ aep) {
  __shared__ float wl[3 * EDIM * NHEAD];
  int t = threadIdx.x;
  if (t < 3 * EDIM * NHEAD) wl[t] = wea[t];
  __syncthreads();
  int pos = blockIdx.x * 256 + t;
  if (pos >= NE) return;
  int e = perm[pos];
  srcp[pos] = src[e];
  float ea[EDIM];
#pragma unroll
  for (int k = 0; k < EDIM; k += 4) {
    float4 v = *(const float4*)&edge_attr[(size_t)e * EDIM + k];
    ea[k] = v.x; ea[k + 1] = v.y; ea[k + 2] = v.z; ea[k + 3] = v.w;
  }
#pragma unroll
  for (int l = 0; l < 3; ++l) {
    float a0 = 0.f, a1 = 0.f, a2 = 0.f, a3 = 0.f;
#pragma unroll
    for (int k = 0; k < EDIM; ++k) {
      float ev = ea[k];
      a0 += ev * wl[l * 64 + k * 4 + 0];
      a1 += ev * wl[l * 64 + k * 4 + 1];
      a2 += ev * wl[l * 64 + k * 4 + 2];
      a3 += ev * wl[l * 64 + k * 4 + 3];
    }
    *(float4*)&aep[(size_t)l * NE * 4 + (size_t)pos * 4] = make_float4(a0, a1, a2, a3);
  }
}

// ---------------- conv GEMM via MFMA: full-K staged once, ONE barrier, then barrier-free MFMA.
template <int K>
__global__ __launch_bounds__(256) void k_conv_mfma(const unsigned short* __restrict__ xin,
                                                   const unsigned short* __restrict__ wt,
                                                   const unsigned short* __restrict__ wsd,
                                                   unsigned short* __restrict__ htb,
                                                   float* __restrict__ asrc, float* __restrict__ adst) {
  constexpr int NC = K / 8;            // kc chunks
  constexpr int CA = NC * 128;         // A/B chunk count
  constexpr int CB2 = NC * 16;         // wsd chunk count
  __shared__ unsigned short As[CA * 8];
  __shared__ unsigned short Bs[CA * 8];
  __shared__ unsigned short Bs2[CB2 * 8];
  int t = threadIdx.x;
  int n0 = blockIdx.x * 128;
  int lane = t & 63;
  int wave = t >> 6;
  int wr = wave >> 1, wc = wave & 1;

  floatx4 acc[4][4];
  floatx4 acce[4];
#pragma unroll
  for (int a = 0; a < 4; ++a) {
    acce[a] = (floatx4){0.f, 0.f, 0.f, 0.f};
#pragma unroll
    for (int b = 0; b < 4; ++b) acc[a][b] = (floatx4){0.f, 0.f, 0.f, 0.f};
  }

  // stage everything (coalesced, per-lane gptr)
  for (int c0 = wave * 64; c0 < CA; c0 += 256) {
    int kc = c0 >> 7, row0 = c0 & 127;
    async16(As + (size_t)c0 * 8, xin + ((size_t)kc * NNP + n0 + row0 + lane) * 8);
    async16(Bs + (size_t)c0 * 8, wt + ((size_t)c0 + lane) * 8);
  }
  if (wave * 64 < CB2) async16(Bs2 + (size_t)wave * 64 * 8, wsd + ((size_t)wave * 64 + lane) * 8);

  __syncthreads();  // the only barrier: all staging drained

  int frow = lane & 15, fkc = lane >> 4;
#pragma unroll
  for (int kk = 0; kk < K / 32; ++kk) {
    const unsigned short* ab = As + (size_t)(kk * 4 + fkc) * 128 * 8;
    const unsigned short* bb = Bs + (size_t)(kk * 4 + fkc) * 128 * 8;
    short8 af[4], bf[4], bf2;
#pragma unroll
    for (int ti = 0; ti < 4; ++ti) af[ti] = *(const short8*)(ab + ((size_t)(wr * 64 + frow + ti * 16)) * 8);
#pragma unroll
    for (int tj = 0; tj < 4; ++tj) bf[tj] = *(const short8*)(bb + ((size_t)(wc * 64 + frow + tj * 16)) * 8);
    bf2 = *(const short8*)(Bs2 + ((size_t)(kk * 4 + fkc) * 16 + frow) * 8);
#pragma unroll
    for (int ti = 0; ti < 4; ++ti)
#pragma unroll
      for (int tj = 0; tj < 4; ++tj)
        acc[ti][tj] = __builtin_amdgcn_mfma_f32_16x16x32_bf16(af[ti], bf[tj], acc[ti][tj], 0, 0, 0);
    if (wc == 0) {
#pragma unroll
      for (int ti = 0; ti < 4; ++ti)
        acce[ti] = __builtin_amdgcn_mfma_f32_16x16x32_bf16(af[ti], bf2, acce[ti], 0, 0, 0);
    }
  }

  int q = lane & 15;
  int colg = wc * 64 + q;
#pragma unroll
  for (int ti = 0; ti < 4; ++ti) {
    int rowb = n0 + wr * 64 + ti * 16 + (lane >> 4) * 4;
#pragma unroll
    for (int r = 0; r < 4; ++r) {
      int row = rowb + r;
      if (row < NN) {
        htb[(size_t)row * HC + colg] = f2bf(acc[ti][0][r]);
        htb[(size_t)row * HC + colg + 16] = f2bf(acc[ti][1][r]);
        htb[(size_t)row * HC + colg + 32] = f2bf(acc[ti][2][r]);
        htb[(size_t)row * HC + colg + 48] = f2bf(acc[ti][3][r]);
        if (wc == 0 && q < 8) {
          float v = acce[ti][r];
          if (q < 4) asrc[row * 4 + q] = v;
          else adst[row * 4 + (q - 4)] = v;
        }
      }
    }
  }
}

// ---------------- fused alpha + softmax + aggregate. One wave per node, NO block barriers:
// exs[wid] is wave-private; same-wave DS ordering + threadfence keeps write->read safe.
__global__ __launch_bounds__(256) void k_aggregate(
    const unsigned short* __restrict__ htb, const int* __restrict__ srcp,
    const float* __restrict__ aep, const float* __restrict__ asrc, const float* __restrict__ adst,
    const int* __restrict__ row_start, const float* __restrict__ bias,
    unsigned short* __restrict__ XBp, int kcoff) {
  __shared__ float exs[4][MAXCH][4];
  int t = threadIdx.x;
  int lane = t & 63, wid = t >> 6;
  int n = blockIdx.x * 4 + wid;
  if (n >= NN) return;  // whole wave exits; no barriers in this kernel
  int rs = row_start[n], re = row_start[n + 1];
  int nchunk = (re - rs + MAXCH - 1) / MAXCH;
  int q = lane & 15, g = lane >> 4;
  int h = q >> 2;
  float4 ad4 = *(const float4*)&adst[n * 4];
  float acc[8];
#pragma unroll
  for (int j = 0; j < 8; ++j) acc[j] = 0.f;
  float d0 = 0.f, d1 = 0.f, d2 = 0.f, d3 = 0.f;

  for (int cc = 0; cc < nchunk; ++cc) {
    int base = rs + cc * MAXCH;
    int m = re - base;
    if (m > MAXCH) m = MAXCH;
    if (lane < m) {
      int i = base + lane;
      int s = srcp[i];
      float4 ae = *(const float4*)&aep[(size_t)i * 4];
      float4 as4 = *(const float4*)&asrc[s * 4];
      float4 ex;
      ex.x = __expf(lrelu(as4.x + ad4.x + ae.x, 0.2f));
      ex.y = __expf(lrelu(as4.y + ad4.y + ae.y, 0.2f));
      ex.z = __expf(lrelu(as4.z + ad4.z + ae.z, 0.2f));
      ex.w = __expf(lrelu(as4.w + ad4.w + ae.w, 0.2f));
      *(float4*)&exs[wid][lane][0] = ex;
      d0 += ex.x; d1 += ex.y; d2 += ex.z; d3 += ex.w;
    }
    __threadfence_block();  // wave-local LDS writes visible (no s_barrier)
    int iters = (m + 7) >> 3;
    for (int kk = 0; kk < iters; ++kk) {
      int ii0 = kk * 8 + g;
      int ii1 = ii0 + 4;
      int i0 = base + ((ii0 < m) ? ii0 : 0);
      int i1 = base + ((ii1 < m) ? ii1 : 0);
      int s0 = srcp[i0];
      int s1 = srcp[i1];
      uint4 h0 = *(const uint4*)(htb + (size_t)s0 * HC + q * 8);
      uint4 h1 = *(const uint4*)(htb + (size_t)s1 * HC + q * 8);
      float w0 = (ii0 < m) ? exs[wid][ii0][h] : 0.f;
      float w1 = (ii1 < m) ? exs[wid][ii1][h] : 0.f;
      acc[0] += w0 * bflo(h0.x) + w1 * bflo(h1.x);
      acc[1] += w0 * bfhi(h0.x) + w1 * bfhi(h1.x);
      acc[2] += w0 * bflo(h0.y) + w1 * bflo(h1.y);
      acc[3] += w0 * bfhi(h0.y) + w1 * bfhi(h1.y);
      acc[4] += w0 * bflo(h0.z) + w1 * bflo(h1.z);
      acc[5] += w0 * bfhi(h0.z) + w1 * bfhi(h1.z);
      acc[6] += w0 * bflo(h0.w) + w1 * bflo(h1.w);
      acc[7] += w0 * bfhi(h0.w) + w1 * bfhi(h1.w);
    }
    __threadfence_block();  // reads done before next chunk overwrites exs
  }

#pragma unroll
  for (int mm = 1; mm < 64; mm <<= 1) {
    d0 += __shfl_xor(d0, mm, 64);
    d1 += __shfl_xor(d1, mm, 64);
    d2 += __shfl_xor(d2, mm, 64);
    d3 += __shfl_xor(d3, mm, 64);
  }
#pragma unroll
  for (int j = 0; j < 8; ++j) {
    acc[j] += __shfl_xor(acc[j], 16, 64);
    acc[j] += __shfl_xor(acc[j], 32, 64);
  }
  if (g == 0) {
    float dh = (h == 0) ? d0 : ((h == 1) ? d1 : ((h == 2) ? d2 : d3));
    float inv = 1.f / (dh + 1e-16f);
    unsigned int w[4];
#pragma unroll
    for (int j = 0; j < 4; ++j) {
      float v0 = acc[2 * j] * inv + bias[q * 8 + 2 * j];
      float v1 = acc[2 * j + 1] * inv + bias[q * 8 + 2 * j + 1];
      w[j] = (unsigned int)f2bf(v0) | ((unsigned int)f2bf(v1) << 16);
    }
    *(uint4*)&XBp[((size_t)(kcoff + q) * NNP + n) * 8] = make_uint4(w[0], w[1], w[2], w[3]);
  }
}

// ---------------- global add pool from XB kc 32..47 (= h3)
__global__ __launch_bounds__(128) void k_pool(const unsigned short* __restrict__ XBp, const int* __restrict__ gs,
                                              float* __restrict__ hpool) {
  int g = blockIdx.x;
  int j = threadIdx.x;
  int kc = 32 + (j >> 3), sb = j & 7;
  int s = gs[g], e = gs[g + 1];
  float acc = 0.f;
  for (int i = s; i < e; ++i) acc += bflo((unsigned int)XBp[((size_t)kc * NNP + i) * 8 + sb]);
  hpool[(size_t)g * HC + j] = acc;
}

// ---------------- ph[g,0:512] = hpool[g,0:128] @ lw1[384:512, 0:512]
__global__ __launch_bounds__(256) void k_pool_gemm(const float* __restrict__ hpool, const float* __restrict__ lw1,
                                                   float* __restrict__ ph) {
  __shared__ float hp[16][128];
  int t = threadIdx.x;
  int j0 = blockIdx.x * 128;
  int g0 = blockIdx.y * 16;
  int jj = t & 127, gg = t >> 7;
#pragma unroll
  for (int i = 0; i < 8; ++i) {
    int q = t + 256 * i;
    int row = q >> 7, col = q & 127;
    hp[row][col] = hpool[(size_t)(g0 + row) * HC + col];
  }
  __syncthreads();
  float acc[8];
#pragma unroll
  for (int i = 0; i < 8; ++i) acc[i] = 0.f;
  for (int k = 0; k < HC; ++k) {
    float wv = lw1[(size_t)(384 + k) * 512 + j0 + jj];
#pragma unroll
    for (int gi = 0; gi < 8; ++gi) acc[gi] += hp[gg + 2 * gi][k] * wv;
  }
#pragma unroll
  for (int gi = 0; gi < 8; ++gi) ph[(size_t)(g0 + gg + 2 * gi) * 512 + j0 + jj] = acc[gi];
}

// ---------------- fused MLP via bf16 MFMA, ping-pong LDS double-buffer, ONE barrier/iter.
// STAGE evaluates args into locals first (r8 bug: macro-captured loop var corrupted buffer idx).
__global__ __launch_bounds__(256, 2) void k_mlp_mfma(
    const unsigned short* __restrict__ XBp, const unsigned short* __restrict__ lw1img,
    const float* __restrict__ ph, const int* __restrict__ batch,
    const float* __restrict__ lb1, const float* __restrict__ lw2,
    float* __restrict__ out) {
  __shared__ unsigned short As[2 * 512 * 8];    // 16 KB (2 bufs)
  __shared__ unsigned short Bs[2 * 1024 * 8];   // 32 KB
  int t = threadIdx.x;
  int jh = blockIdx.x;         // 0,1
  int n0 = blockIdx.y * 128;
  int lane = t & 63;
  int wave = t >> 6;
  int wr = wave >> 1, wc = wave & 1;
  int kadd = wave >> 1, rb = (wave & 1) * 64;
  const unsigned short* bimg = lw1img + (size_t)jh * 48 * 256 * 8;

  floatx4 acc[4][8];
#pragma unroll
  for (int a = 0; a < 4; ++a)
#pragma unroll
    for (int b = 0; b < 8; ++b) acc[a][b] = (floatx4){0.f, 0.f, 0.f, 0.f};

#define STAGE(bufv, kbv)                                                                  \
  do {                                                                                    \
    const int _bf = (bufv);                                                               \
    const int _kb = (kbv);                                                                \
    _Pragma("unroll") for (int pp = 0; pp < 2; ++pp)                                      \
        async16(As + ((size_t)_bf * 512 + pp * 256 + wave * 64) * 8,                      \
                XBp + ((size_t)(_kb + pp * 2 + kadd) * NNP + n0 + rb + lane) * 8);        \
    _Pragma("unroll") for (int pp = 0; pp < 4; ++pp)                                      \
        async16(Bs + ((size_t)_bf * 1024 + pp * 256 + wave * 64) * 8,                     \
                bimg + ((size_t)(_kb + pp) * 256 + wave * 64 + lane) * 8);                \
  } while (0)

  STAGE(0, 0);

  int frow = lane & 15, fkc = lane >> 4;
  for (int kk = 0; kk < 12; ++kk) {
    int p = kk & 1;
    __syncthreads();  // staging into buf p (issued last iter) drained; prior reads of buf p done
    const unsigned short* ab = As + (size_t)p * 512 * 8 + ((size_t)fkc * 128 + wr * 64 + frow) * 8;
    const unsigned short* bb = Bs + (size_t)p * 1024 * 8 + ((size_t)fkc * 256 + wc * 128 + frow) * 8;
    short8 af[4], bf[8];
#pragma unroll
    for (int ti = 0; ti < 4; ++ti) af[ti] = *(const short8*)(ab + (size_t)ti * 16 * 8);
#pragma unroll
    for (int tj = 0; tj < 8; ++tj) bf[tj] = *(const short8*)(bb + (size_t)tj * 16 * 8);
    if (kk < 11) STAGE(1 - p, (kk + 1) * 4);
#pragma unroll
    for (int ti = 0; ti < 4; ++ti)
#pragma unroll
      for (int tj = 0; tj < 8; ++tj)
        acc[ti][tj] = __builtin_amdgcn_mfma_f32_16x16x32_bf16(af[ti], bf[tj], acc[ti][tj], 0, 0, 0);
  }
#undef STAGE

  int colg = jh * 256 + wc * 128 + (lane & 15);
#pragma unroll
  for (int ti = 0; ti < 4; ++ti) {
    int rowb = n0 + wr * 64 + ti * 16 + (lane >> 4) * 4;
#pragma unroll
    for (int r = 0; r < 4; ++r) {
      int row = rowb + r;
      int rc = (row < NN) ? row : 0;
      int bg = batch[rc];
      float partial = 0.f;
#pragma unroll
      for (int tj = 0; tj < 8; ++tj) {
        int j = colg + tj * 16;
        float v = acc[ti][tj][r] + ph[(size_t)bg * 512 + j] + lb1[j];
        partial += lrelu(v, 0.01f) * lw2[j];
      }
#pragma unroll
      for (int m = 1; m < 16; m <<= 1) partial += __shfl_xor(partial, m, 16);
      if ((lane & 15) == 0 && row < NN) atomicAdd(&out[row], partial);
    }
  }
}

extern "C" void kernel_launch(void* const* d_in, const int* in_sizes, int n_in,
                              void* d_out, int out_size, void* d_ws, size_t ws_size,
                              hipStream_t stream) {
  const float* x = (const float*)d_in[0];
  const int* edge_index = (const int*)d_in[1];
  const int* src = edge_index;
  const int* dstp = edge_index + NE;
  const float* edge_attr = (const float*)d_in[2];
  const int* batch = (const int*)d_in[3];
  const float* W[3] = {(const float*)d_in[4], (const float*)d_in[10], (const float*)d_in[16]};
  const float* as_[3] = {(const float*)d_in[5], (const float*)d_in[11], (const float*)d_in[17]};
  const float* ad_[3] = {(const float*)d_in[6], (const float*)d_in[12], (const float*)d_in[18]};
  const float* We_[3] = {(const float*)d_in[7], (const float*)d_in[13], (const float*)d_in[19]};
  const float* ae_[3] = {(const float*)d_in[8], (const float*)d_in[14], (const float*)d_in[20]};
  const float* b_[3] = {(const float*)d_in[9], (const float*)d_in[15], (const float*)d_in[21]};
  const float* lw1 = (const float*)d_in[22];
  const float* lb1 = (const float*)d_in[23];
  const float* lw2 = (const float*)d_in[24];
  const float* lb2 = (const float*)d_in[25];
  float* out = (float*)d_out;

  // workspace carve-up (floats unless noted)
  float* f = (float*)d_ws;
  size_t o = 0;
  float* asrc = f + o;  o += (size_t)NN * NHEAD;
  float* adst = f + o;  o += (size_t)NN * NHEAD;
  float* wea = f + o;   o += 256;
  float* hpool = f + o; o += (size_t)NG * HC;
  float* aep = f + o;   o += (size_t)3 * NE * 4;
  // xb0 (k-major [8][NNP][8] bf16) overlaid with ph (fp32 [NG][512]): xb0 dead before ph written
  unsigned short* xb0 = (unsigned short*)(f + o);
  float* ph = (float*)xb0;
  o += (size_t)8 * NNP * 8 / 2;
  unsigned short* htb = (unsigned short*)(f + o);   o += (size_t)NN * HC / 2;
  unsigned short* XB = (unsigned short*)(f + o);    o += (size_t)48 * NNP * 8 / 2;
  unsigned short* wtb = (unsigned short*)(f + o);   o += (size_t)(128 * 64 + 2 * 128 * 128) / 2;
  unsigned short* lw1img = (unsigned short*)(f + o); o += (size_t)2 * 48 * 256 * 8 / 2;
  unsigned short* wsdb = (unsigned short*)(f + o);  o += (size_t)3 * 2048 / 2;
  int* row_start = (int*)(f + o);
  int* cnt = row_start + (NN + 1);
  int* fill = cnt + NN;
  int* aux = fill + NN;
  int* gs = aux + 256;
  int* perm = gs + (NG + 1);
  int* srcp = perm + NE;

  const int NB = (NN + 255) / 256;
  const int EB = (NE + 255) / 256;

  hipMemsetAsync(cnt, 0, (size_t)2 * NN * sizeof(int), stream);  // cnt + fill

  k_prep<<<PREP_BLOCKS, 256, 0, stream>>>(
      We_[0], ae_[0], We_[1], ae_[1], We_[2], ae_[2], wea,
      W[0], as_[0], ad_[0], W[1], as_[1], ad_[1], W[2], as_[2], ad_[2], wsdb,
      lw1, lw1img, wtb, x, xb0, batch, gs, out, lb2, dstp, cnt);
  k_scan1<<<NB, 256, 0, stream>>>(cnt, row_start, aux);
  k_scan2<<<1, 256, 0, stream>>>(aux, NB);
  k_scan3<<<NB, 256, 0, stream>>>(row_start, aux);
  k_scatter<<<EB, 256, 0, stream>>>(dstp, row_start, fill, perm);
  k_permute<<<EB, 256, 0, stream>>>(perm, src, edge_attr, wea, srcp, aep);

  const int CONVB = NNP / 128;  // 391
  unsigned short* wt_l[3] = {wtb, wtb + 8192, wtb + 24576};
  for (int l = 0; l < 3; ++l) {
    unsigned short* wsd_l = wsdb + (size_t)l * 2048;
    const unsigned short* xin = (l == 0) ? xb0 : (XB + (size_t)(l - 1) * 16 * NNP * 8);
    if (l == 0)
      k_conv_mfma<64><<<CONVB, 256, 0, stream>>>(xin, wt_l[0], wsd_l, htb, asrc, adst);
    else
      k_conv_mfma<128><<<CONVB, 256, 0, stream>>>(xin, wt_l[l], wsd_l, htb, asrc, adst);
    k_aggregate<<<(NN + 3) / 4, 256, 0, stream>>>(htb, srcp, aep + (size_t)l * NE * 4, asrc, adst,
                                                  row_start, b_[l], XB, l * 16);
  }

  k_pool<<<NG, 128, 0, stream>>>(XB, gs, hpool);
  k_pool_gemm<<<dim3(4, NG / 16), 256, 0, stream>>>(hpool, lw1, ph);
  k_mlp_mfma<<<dim3(2, NNP / 128), 256, 0, stream>>>(XB, lw1img, ph, batch, lb1, lw2, out);
}